// Round 21
// baseline (58.438 us; speedup 1.0000x reference)
//
#include <hip/hip_runtime.h>
#include <stdint.h>

// Problem dims (VectorNet): B=64, NA=49, NM=19, P=128, IN=64, H=64, OUT=60, H2=128
#define B_    64
#define NA_   49
#define NM_   19
#define P_    128
#define OUT_  60
#define AGRID 32          // agent: 2 graphs/block (row bases 0,64; 4 tiles)
#define MGRID 1366        // map: 6 graphs/block (114 rows, 4 tiles); tail ng=2
// X tile: 128 rows x 128 ch bf16, XOR-swizzled, row stride 256B
#define XR     128
#define XBYTES (XR * 256)            // 32768
#define WBBYTES 16384                // W LDS buffer: 1024 uint4 (largest layer)
#define PBYTES (9 * 64 * 4)          // 768
#define SMEMB  (XBYTES + WBBYTES + PBYTES)   // 49920 -> 3 blocks/CU
// d_ws layout: feats | packed W^T | was/wad
#define FEATS_BYTES (129 * 64 * 128 * 4)     // 4227072
#define WT_UINTS_PER_SET 10240               // l0:2048, l1:4096, l2:4096 (uints)
#define WT_BYTES (2 * WT_UINTS_PER_SET * 4)  // 81920

typedef __bf16 bf16x8 __attribute__((ext_vector_type(8)));
typedef float  f32x16 __attribute__((ext_vector_type(16)));
typedef unsigned short ushort_t;

__device__ __forceinline__ unsigned int cvt_pk_bf16(float lo, float hi) {
  unsigned int r;
  asm("v_cvt_pk_bf16_f32 %0, %1, %2" : "=v"(r) : "v"(lo), "v"(hi));
  return r;
}

__device__ __forceinline__ f32x16 zero16() {
  f32x16 z;
#pragma unroll
  for (int i = 0; i < 16; ++i) z[i] = 0.f;
  return z;
}

// swizzled X address: row stride 256B, byte ^= (row&7)<<4
__device__ __forceinline__ int xswz(int row, int byteoff) {
  return row * 256 + (byteoff ^ ((row & 7) << 4));
}

// ---------------------------------------------------------------------------
// Prep: blocks 0..79 pack W^T (bf16, A-fragment order, verified r8):
//   uint index = ((ks*2+mt)*64 + lr*2 + hi)*4 + j2
//   value = pack(W[k0*64+ch], W[(k0+1)*64+ch]), k0=ks*16+hi*8+j2*2, ch=mt*32+lr
// Block 80: was/wad = fcw @ attnw[:128], fcw @ attnw[128:]  (wave-per-row)
// ---------------------------------------------------------------------------
__global__ void prep_kernel(
    const float* __restrict__ aw0, const float* __restrict__ aw1,
    const float* __restrict__ aw2, const float* __restrict__ mw0,
    const float* __restrict__ mw1, const float* __restrict__ mw2,
    const float* __restrict__ fcw, const float* __restrict__ attnw,
    unsigned int* __restrict__ dst, float* __restrict__ waswad)
{
  if (blockIdx.x == 80) {
    const int lane = threadIdx.x & 63, wid = threadIdx.x >> 6;
    float a0 = attnw[lane],       a1 = attnw[64 + lane];
    float d0 = attnw[128 + lane], d1 = attnw[192 + lane];
    for (int r = wid; r < 128; r += 4) {
      float w0 = fcw[r * 128 + lane], w1 = fcw[r * 128 + 64 + lane];
      float s1 = w0 * a0 + w1 * a1;
      float s2 = w0 * d0 + w1 * d1;
#pragma unroll
      for (int off = 32; off; off >>= 1) {
        s1 += __shfl_xor(s1, off);
        s2 += __shfl_xor(s2, off);
      }
      if (lane == 0) { waswad[r] = s1; waswad[128 + r] = s2; }
    }
    return;
  }
  const int U = blockIdx.x * 256 + threadIdx.x;
  const int set = U / WT_UINTS_PER_SET;
  const int u = U - set * WT_UINTS_PER_SET;
  int layer, ul;
  if (u < 2048)      { layer = 0; ul = u; }
  else if (u < 6144) { layer = 1; ul = u - 2048; }
  else               { layer = 2; ul = u - 6144; }
  const float* W;
  if (set == 0) W = (layer == 0) ? aw0 : (layer == 1 ? aw1 : aw2);
  else          W = (layer == 0) ? mw0 : (layer == 1 ? mw1 : mw2);
  int j2 = ul & 3, t = ul >> 2;
  int hi = t & 1; t >>= 1;
  int lr = t & 31; t >>= 5;
  int mt = t & 1;
  int ks = t >> 1;
  int k0 = ks * 16 + hi * 8 + j2 * 2;
  int ch = mt * 32 + lr;
  dst[U] = cvt_pk_bf16(W[k0 * 64 + ch], W[(k0 + 1) * 64 + ch]);
}

// ---------------------------------------------------------------------------
// One 32-row x 64-chan layer tile (verified r3..r20 math):
//   v_mfma_f32_32x32x16_bf16, D = W^T (A) x^T (B)
//     A: row=lane&31 (chan), k=(lane>>5)*8+j ; B: col=lane&31 (graph-row)
//     D: col=lane&31 (row), chan=(reg&3)+8*(reg>>2)+4*(lane>>5)
//   B-fragments preloaded (deep LDS pipeline), A-pairs JIT from the dense
//   per-layer LDS W buffer. LN(64) in-place + one shfl_xor(32).
//   Lanes lr>=vr produce garbage (contained: D-col==B-row) and are guarded.
// ---------------------------------------------------------------------------
template<int KS>
__device__ __forceinline__ void tile_layer(
    const char* __restrict__ wl,    // LDS W buffer (packed fragment order)
    char* __restrict__ xs, int xrow0, int vr,
    const float* __restrict__ Pb, const float* __restrict__ Pg,
    const float* __restrict__ Pn)
{
  const int lane = threadIdx.x & 63;
  const int lr   = lane & 31;
  const int hi   = lane >> 5;
  const int ch4  = hi * 4;
  const int br   = xrow0 + lr;
  const int wo   = (lr * 2 + hi) * 16;   // lane's byte offset within 64-frag group

  // preload all B-fragments (independent LDS reads, deep pipeline)
  bf16x8 bfr[KS];
#pragma unroll
  for (int ks = 0; ks < KS; ++ks)
    bfr[ks] = *(const bf16x8*)(xs + xswz(br, ks * 32 + hi * 16));

  f32x16 acc0 = zero16(), acc1 = zero16();
#pragma unroll
  for (int ks = 0; ks < KS; ++ks) {
    bf16x8 a0 = *(const bf16x8*)(wl + (ks * 2 + 0) * 1024 + wo);
    bf16x8 a1 = *(const bf16x8*)(wl + (ks * 2 + 1) * 1024 + wo);
    acc0 = __builtin_amdgcn_mfma_f32_32x32x16_bf16(a0, bfr[ks], acc0, 0, 0, 0);
    acc1 = __builtin_amdgcn_mfma_f32_32x32x16_bf16(a1, bfr[ks], acc1, 0, 0, 0);
  }

  // ---- bias (in place) + LayerNorm(64) ----
#pragma unroll
  for (int b = 0; b < 4; ++b) {
    float4 t0 = *(const float4*)&Pb[8 * b + ch4];
    float4 t1 = *(const float4*)&Pb[32 + 8 * b + ch4];
    acc0[4*b+0] += t0.x; acc0[4*b+1] += t0.y;
    acc0[4*b+2] += t0.z; acc0[4*b+3] += t0.w;
    acc1[4*b+0] += t1.x; acc1[4*b+1] += t1.y;
    acc1[4*b+2] += t1.z; acc1[4*b+3] += t1.w;
  }
  float s = 0.f, q = 0.f;
#pragma unroll
  for (int r = 0; r < 16; ++r) {
    s += acc0[r] + acc1[r];
    q = fmaf(acc0[r], acc0[r], q);
    q = fmaf(acc1[r], acc1[r], q);
  }
  s += __shfl_xor(s, 32);
  q += __shfl_xor(q, 32);
  float mu   = s * 0.015625f;
  float rstd = rsqrtf(fmaf(q, 0.015625f, -mu * mu) + 1e-5f);

  // ---- gamma/beta + ReLU, pack bf16, guarded swizzled write ----
#pragma unroll
  for (int b = 0; b < 4; ++b) {
    float4 g0 = *(const float4*)&Pg[8 * b + ch4];
    float4 n0 = *(const float4*)&Pn[8 * b + ch4];
    float4 g1 = *(const float4*)&Pg[32 + 8 * b + ch4];
    float4 n1 = *(const float4*)&Pn[32 + 8 * b + ch4];
    float h00 = fmaxf(0.f, fmaf((acc0[4*b+0] - mu) * rstd, g0.x, n0.x));
    float h01 = fmaxf(0.f, fmaf((acc0[4*b+1] - mu) * rstd, g0.y, n0.y));
    float h02 = fmaxf(0.f, fmaf((acc0[4*b+2] - mu) * rstd, g0.z, n0.z));
    float h03 = fmaxf(0.f, fmaf((acc0[4*b+3] - mu) * rstd, g0.w, n0.w));
    float h10 = fmaxf(0.f, fmaf((acc1[4*b+0] - mu) * rstd, g1.x, n1.x));
    float h11 = fmaxf(0.f, fmaf((acc1[4*b+1] - mu) * rstd, g1.y, n1.y));
    float h12 = fmaxf(0.f, fmaf((acc1[4*b+2] - mu) * rstd, g1.z, n1.z));
    float h13 = fmaxf(0.f, fmaf((acc1[4*b+3] - mu) * rstd, g1.w, n1.w));
    if (lr < vr) {
      uint2 u0; u0.x = cvt_pk_bf16(h00, h01); u0.y = cvt_pk_bf16(h02, h03);
      uint2 u1; u1.x = cvt_pk_bf16(h10, h11); u1.y = cvt_pk_bf16(h12, h13);
      *(uint2*)(xs + xswz(br, 16 * b + 8 * hi)) = u0;
      *(uint2*)(xs + xswz(br, 64 + 16 * b + 8 * hi)) = u1;
    }
  }
}

// stage one layer's packed W^T from global into the LDS W buffer (coalesced)
__device__ __forceinline__ void stage_w(const uint4* __restrict__ src,
                                        char* __restrict__ wbuf, int cnt) {
  uint4* d = (uint4*)wbuf;
  for (int i = threadIdx.x; i < cnt; i += 256) d[i] = src[i];
}

// map neighbor-max (top-2) for graph g / channel c, register row cache;
// h>=0 so bf16 bits compare as uint16
__device__ __forceinline__ void nmax_one(char* xs, int g, int c) {
  const int rb = g * NM_;
  unsigned int xv[NM_];
  unsigned int m1 = 0, m2 = 0;
#pragma unroll
  for (int n = 0; n < NM_; ++n) {
    xv[n] = *(const ushort_t*)(xs + xswz(rb + n, 2 * c));
    if (xv[n] > m1) { m2 = m1; m1 = xv[n]; } else if (xv[n] > m2) m2 = xv[n];
  }
#pragma unroll
  for (int n = 0; n < NM_; ++n)
    *(ushort_t*)(xs + xswz(rb + n, 128 + 2 * c)) =
        (ushort_t)((xv[n] == m1) ? m2 : m1);
}

// agent-pair neighbor-max: threads 0..127 -> (g=tid>>6 row base g*64, c);
// streaming top-2 over 49 rows (no register cache — 49 too large)
__device__ __forceinline__ void nmax_agent2(char* xs) {
  const int tid = threadIdx.x;
  if (tid >= 128) return;
  const int g = tid >> 6, c = tid & 63;
  const int rb = g * 64;
  unsigned int m1 = 0, m2 = 0;
  for (int n = 0; n < NA_; ++n) {
    unsigned int x = *(const ushort_t*)(xs + xswz(rb + n, 2 * c));
    if (x > m1) { m2 = m1; m1 = x; } else if (x > m2) m2 = x;
  }
  for (int n = 0; n < NA_; ++n) {
    unsigned int x = *(const ushort_t*)(xs + xswz(rb + n, 2 * c));
    *(ushort_t*)(xs + xswz(rb + n, 128 + 2 * c)) =
        (ushort_t)((x == m1) ? m2 : m1);
  }
}

__device__ __forceinline__ void stage_params(
    const float* b0, const float* g0, const float* n0,
    const float* b1, const float* g1, const float* n1,
    const float* b2, const float* g2, const float* n2, float* Pp)
{
  const int tid = threadIdx.x;
  if (tid < 64) {
    Pp[      tid] = b0[tid]; Pp[ 64 + tid] = g0[tid]; Pp[128 + tid] = n0[tid];
    Pp[192 + tid] = b1[tid]; Pp[256 + tid] = g1[tid]; Pp[320 + tid] = n1[tid];
    Pp[384 + tid] = b2[tid]; Pp[448 + tid] = g2[tid]; Pp[512 + tid] = n2[tid];
  }
}

// ---------------------------------------------------------------------------
__global__ __launch_bounds__(256, 3) void subnet13(
    const float* __restrict__ agent, const float* __restrict__ mapf,
    const float* __restrict__ ab0, const float* __restrict__ ag0,
    const float* __restrict__ an0, const float* __restrict__ ab1,
    const float* __restrict__ ag1, const float* __restrict__ an1,
    const float* __restrict__ ab2, const float* __restrict__ ag2,
    const float* __restrict__ an2, const float* __restrict__ mb0,
    const float* __restrict__ mg0, const float* __restrict__ mn0,
    const float* __restrict__ mb1, const float* __restrict__ mg1,
    const float* __restrict__ mn1, const float* __restrict__ mb2,
    const float* __restrict__ mg2, const float* __restrict__ mn2,
    const uint4* __restrict__ wt, float* __restrict__ feats)
{
  __shared__ __align__(16) char smem[SMEMB];
  char*  xs   = smem;
  char*  wbuf = smem + XBYTES;
  float* Pp   = (float*)(smem + XBYTES + WBBYTES);
  const int tid = threadIdx.x;
  const int wid = tid >> 6;

  if (blockIdx.x < AGRID) {
    // ---- agent: 2 graphs/block at row bases 0,64 (4 tiles, valid
    // 32,17,32,17), barriers; graphs 2*bid and 2*bid+1 ----
    const int bid = blockIdx.x;
    const int vr = (wid & 1) ? 17 : 32;
    for (int i = tid; i < 2 * NA_ * 16; i += 256) {
      int g = i / (NA_ * 16);
      int rem = i - g * (NA_ * 16);
      int row = rem >> 4, k4 = (rem & 15) * 4;
      float4 v = *(const float4*)&agent[((size_t)(2 * bid + g) * NA_ + row) * 64 + k4];
      uint2 u; u.x = cvt_pk_bf16(v.x, v.y); u.y = cvt_pk_bf16(v.z, v.w);
      *(uint2*)(xs + xswz(g * 64 + row, 8 * (rem & 15))) = u;
    }
    stage_w(wt, wbuf, 512);
    stage_params(ab0, ag0, an0, ab1, ag1, an1, ab2, ag2, an2, Pp);
    __syncthreads();
    tile_layer<4>(wbuf, xs, wid * 32, vr, Pp, Pp + 64, Pp + 128);
    __syncthreads();
    nmax_agent2(xs);
    stage_w(wt + 512, wbuf, 1024);
    __syncthreads();
    tile_layer<8>(wbuf, xs, wid * 32, vr, Pp + 192, Pp + 256, Pp + 320);
    __syncthreads();
    nmax_agent2(xs);
    stage_w(wt + 1536, wbuf, 1024);
    __syncthreads();
    tile_layer<8>(wbuf, xs, wid * 32, vr, Pp + 384, Pp + 448, Pp + 512);
    __syncthreads();
    if (tid < 128) {  // poly per (g,c): both halves = max over 49 nodes
      const int g = tid >> 6, c = tid & 63;
      const int rb = g * 64;
      unsigned int m1 = 0;
      for (int n = 0; n < NA_; ++n) {
        unsigned int x = *(const ushort_t*)(xs + xswz(rb + n, 2 * c));
        m1 = x > m1 ? x : m1;
      }
      float f = __uint_as_float(m1 << 16);
      size_t slot = (size_t)(2 * bid + g);
      feats[slot * 128 + c] = f;
      feats[slot * 128 + 64 + c] = f;
    }
  } else {
    // ---- map: 6 graphs dense-packed (114 rows, 4 tiles -> 4 busy waves);
    // tail block ng=2 (38 rows). W staged per layer into LDS; restage
    // overlaps nmax (disjoint LDS regions). Pad-row garbage is confined
    // to lanes lr>=vr (write-guarded; LN lane pairs share lr). ----
    const uint4* wtm = wt + 2560;   // set 1 = map weights
    const int mbid = blockIdx.x - AGRID;
    const int gbase = mbid * 6;
    const int ng = (gbase + 6 <= P_ * B_) ? 6 : (P_ * B_ - gbase);
    const int rows = ng * NM_;
    int vr = rows - wid * 32;       // this wave's valid rows in its tile
    vr = vr > 32 ? 32 : vr;
    for (int i = tid; i < rows * 16; i += 256) {
      int row = i >> 4, k4 = (i & 15) * 4;
      float4 v = *(const float4*)&mapf[((size_t)gbase * NM_ + row) * 64 + k4];
      uint2 u; u.x = cvt_pk_bf16(v.x, v.y); u.y = cvt_pk_bf16(v.z, v.w);
      *(uint2*)(xs + xswz(row, 8 * (i & 15))) = u;
    }
    stage_w(wtm, wbuf, 512);
    stage_params(mb0, mg0, mn0, mb1, mg1, mn1, mb2, mg2, mn2, Pp);
    __syncthreads();
    if (vr > 0) tile_layer<4>(wbuf, xs, wid * 32, vr, Pp, Pp + 64, Pp + 128);
    __syncthreads();
    for (int i = tid; i < ng * 64; i += 256) nmax_one(xs, i >> 6, i & 63);
    stage_w(wtm + 512, wbuf, 1024);
    __syncthreads();
    if (vr > 0) tile_layer<8>(wbuf, xs, wid * 32, vr,
                              Pp + 192, Pp + 256, Pp + 320);
    __syncthreads();
    for (int i = tid; i < ng * 64; i += 256) nmax_one(xs, i >> 6, i & 63);
    stage_w(wtm + 1536, wbuf, 1024);
    __syncthreads();
    if (vr > 0) tile_layer<8>(wbuf, xs, wid * 32, vr,
                              Pp + 384, Pp + 448, Pp + 512);
    __syncthreads();
    for (int i = tid; i < ng * 64; i += 256) {  // poly per (g,c)
      const int g = i >> 6, c = i & 63;
      const int rb = g * NM_;
      unsigned int m1 = 0;
      for (int n = 0; n < NM_; ++n) {
        unsigned int x = *(const ushort_t*)(xs + xswz(rb + n, 2 * c));
        m1 = x > m1 ? x : m1;
      }
      float f = __uint_as_float(m1 << 16);
      size_t slot = (size_t)(B_ + gbase + g);
      feats[slot * 128 + c] = f;
      feats[slot * 128 + 64 + c] = f;
    }
  }
}

// ---------------------------------------------------------------------------
// GAT (only destination node 0 is read) + readout MLP. One block per batch b.
// si phase: 2 threads per dot (halved serial length); rest full-block split.
// ---------------------------------------------------------------------------
__global__ __launch_bounds__(256) void gat_kernel(
    const float* __restrict__ feats,    // [129][B][128] fp32
    const float* __restrict__ fcw,      // [128][128]
    const float* __restrict__ waswad,   // [256] precomputed
    const float* __restrict__ mlpw,     // [128][60]
    const float* __restrict__ mlpb,     // [60]
    float* __restrict__ out)            // [B][60]
{
  const int b = blockIdx.x, tid = threadIdx.x;
  __shared__ float was[128], wad[128];
  __shared__ float si[130];
  __shared__ float alpha[128], red[8];
  __shared__ float up[2][128], ubuf[128], hgp[2][128], op[2][60];

  if (tid < 128) { was[tid] = waswad[tid]; wad[tid] = waswad[128 + tid]; }
  __syncthreads();

  {  // si[1..128]: 2 threads per dot (idx = tid>>1, halves of k)
    const int idx = tid >> 1, half = tid & 1;
    const float* fr = feats + ((size_t)(idx + 1) * B_ + b) * 128 + half * 64;
    const float* wa = was + half * 64;
    float s = 0.f;
    for (int k = 0; k < 64; k += 4) {
      float4 f = *(const float4*)&fr[k];
      s += f.x * wa[k] + f.y * wa[k + 1] + f.z * wa[k + 2] + f.w * wa[k + 3];
    }
    s += __shfl_xor(s, 1);
    if (half == 0) si[idx + 1] = s;
    if (tid < 2) {  // d0 = feats[node 0][b] . wad (threads 0,1 split k)
      const float* f0 = feats + (size_t)b * 128 + tid * 64;
      const float* wd = wad + tid * 64;
      float s2 = 0.f;
      for (int k = 0; k < 64; k += 4) {
        float4 f = *(const float4*)&f0[k];
        s2 += f.x * wd[k] + f.y * wd[k + 1] + f.z * wd[k + 2] + f.w * wd[k + 3];
      }
      s2 += __shfl_xor(s2, 1);
      if (tid == 0) si[129] = s2;
    }
  }
  __syncthreads();

  float d0 = si[129];
  float e = -3.4e38f;
  if (tid < 128) {
    float x = si[tid + 1] + d0;
    e = (x > 0.f) ? x : 0.01f * x;
  }
  float m = e;
#pragma unroll
  for (int off = 32; off; off >>= 1) m = fmaxf(m, __shfl_xor(m, off));
  if ((tid & 63) == 0) red[tid >> 6] = m;
  __syncthreads();
  float mx = fmaxf(red[0], red[1]);
  float p = (tid < 128) ? expf(e - mx) : 0.f;
  float s = p;
#pragma unroll
  for (int off = 32; off; off >>= 1) s += __shfl_xor(s, off);
  if ((tid & 63) == 0) red[4 + (tid >> 6)] = s;
  __syncthreads();
  float denom = red[4] + red[5];
  if (tid < 128) alpha[tid] = p / denom;
  __syncthreads();

  {  // u = sum_t alpha_t feats[t+1][b][:]  — split t over two halves
    const int c = tid & 127, h = tid >> 7;
    const float* fb = feats + ((size_t)(h * 64 + 1) * B_ + b) * 128 + c;
    float u = 0.f;
    for (int t = 0; t < 64; ++t)
      u += alpha[h * 64 + t] * fb[(size_t)t * B_ * 128];
    up[h][c] = u;
  }
  __syncthreads();
  if (tid < 128) ubuf[tid] = up[0][tid] + up[1][tid];
  __syncthreads();

  {  // hg = ubuf @ fcw — split k over two halves
    const int c = tid & 127, h = tid >> 7;
    float sacc = 0.f;
    for (int k = 0; k < 64; ++k)
      sacc += ubuf[h * 64 + k] * fcw[(h * 64 + k) * 128 + c];
    hgp[h][c] = sacc;
  }
  __syncthreads();

  if (tid < 120) {  // out = hg @ mlpw + mlpb — split c over two halves
    const int o = tid % 60, h = tid / 60;
    float sacc = 0.f;
    for (int c = 0; c < 64; ++c)
      sacc += (hgp[0][h * 64 + c] + hgp[1][h * 64 + c]) * mlpw[(h * 64 + c) * OUT_ + o];
    op[h][o] = sacc;
  }
  __syncthreads();
  if (tid < OUT_) out[b * OUT_ + tid] = mlpb[tid] + op[0][tid] + op[1][tid];
}

// ---------------------------------------------------------------------------
extern "C" void kernel_launch(void* const* d_in, const int* in_sizes, int n_in,
                              void* d_out, int out_size, void* d_ws, size_t ws_size,
                              hipStream_t stream) {
  (void)in_sizes; (void)n_in; (void)out_size; (void)ws_size;

  const float* agent = (const float*)d_in[0];   // [B][NA][64]
  const float* mapf  = (const float*)d_in[1];   // [P][B][NM][64]
  // d_in[2] = map_mask (all ones, unused)

  const float* aw0 = (const float*)d_in[3];
  const float* ab0 = (const float*)d_in[4];
  const float* ag0 = (const float*)d_in[5];
  const float* an0 = (const float*)d_in[6];
  const float* aw1 = (const float*)d_in[7];
  const float* ab1 = (const float*)d_in[8];
  const float* ag1 = (const float*)d_in[9];
  const float* an1 = (const float*)d_in[10];
  const float* aw2 = (const float*)d_in[11];
  const float* ab2 = (const float*)d_in[12];
  const float* ag2 = (const float*)d_in[13];
  const float* an2 = (const float*)d_in[14];

  const float* mw0 = (const float*)d_in[15];
  const float* mb0 = (const float*)d_in[16];
  const float* mg0 = (const float*)d_in[17];
  const float* mn0 = (const float*)d_in[18];
  const float* mw1 = (const float*)d_in[19];
  const float* mb1 = (const float*)d_in[20];
  const float* mg1 = (const float*)d_in[21];
  const float* mn1 = (const float*)d_in[22];
  const float* mw2 = (const float*)d_in[23];
  const float* mb2 = (const float*)d_in[24];
  const float* mg2 = (const float*)d_in[25];
  const float* mn2 = (const float*)d_in[26];

  const float* fcw   = (const float*)d_in[27];
  const float* attnw = (const float*)d_in[28];
  const float* mlpw  = (const float*)d_in[29];
  const float* mlpb  = (const float*)d_in[30];

  float* feats = (float*)d_ws;
  unsigned int* wt = (unsigned int*)((char*)d_ws + FEATS_BYTES);
  float* waswad = (float*)((char*)d_ws + FEATS_BYTES + WT_BYTES);
  float* out = (float*)d_out;

  // 1) pack W^T (blocks 0-79) + precompute was/wad (block 80)
  prep_kernel<<<81, 256, 0, stream>>>(aw0, aw1, aw2, mw0, mw1, mw2,
                                      fcw, attnw, wt, waswad);

  // 2) fused agent(32, 2 graphs/block) + map(1366, 6 graphs/block) subnet;
  //    all blocks run 4 busy tile-waves
  subnet13<<<AGRID + MGRID, 256, 0, stream>>>(
      agent, mapf,
      ab0, ag0, an0, ab1, ag1, an1, ab2, ag2, an2,
      mb0, mg0, mn0, mb1, mg1, mn1, mb2, mg2, mn2,
      (const uint4*)wt, feats);

  // 3) GAT column-0 + MLP readout (parallel si, full-block loops)
  gat_kernel<<<B_, 256, 0, stream>>>(feats, fcw, waswad, mlpw, mlpb, out);
}

// Round 22
// 55.881 us; speedup vs baseline: 1.0458x; 1.0458x over previous
//
#include <hip/hip_runtime.h>
#include <stdint.h>

// Problem dims (VectorNet): B=64, NA=49, NM=19, P=128, IN=64, H=64, OUT=60, H2=128
#define B_    64
#define NA_   49
#define NM_   19
#define P_    128
#define OUT_  60
#define AGRID 32          // agent: 2 graphs/block (row bases 0,64; 4 tiles)
#define MGRID 1366        // map: 6 graphs/block (114 rows, 4 tiles); tail ng=2
// X tile: 128 rows x 128 ch bf16, XOR-swizzled, row stride 256B
#define XR     128
#define XBYTES (XR * 256)            // 32768
#define WBBYTES 16384                // W LDS buffer (largest layer)
#define PBYTES (9 * 64 * 4)          // 768
#define SMEMB  (XBYTES + WBBYTES + PBYTES)   // 49920 -> 3 blocks/CU
// d_ws layout: feats | was/wad
#define FEATS_BYTES (129 * 64 * 128 * 4)     // 4227072

typedef __bf16 bf16x8 __attribute__((ext_vector_type(8)));
typedef float  f32x16 __attribute__((ext_vector_type(16)));
typedef unsigned short ushort_t;

__device__ __forceinline__ unsigned int cvt_pk_bf16(float lo, float hi) {
  unsigned int r;
  asm("v_cvt_pk_bf16_f32 %0, %1, %2" : "=v"(r) : "v"(lo), "v"(hi));
  return r;
}

__device__ __forceinline__ f32x16 zero16() {
  f32x16 z;
#pragma unroll
  for (int i = 0; i < 16; ++i) z[i] = 0.f;
  return z;
}

// swizzled X address: row stride 256B, byte ^= (row&7)<<4
__device__ __forceinline__ int xswz(int row, int byteoff) {
  return row * 256 + (byteoff ^ ((row & 7) << 4));
}

// ---------------------------------------------------------------------------
// Direct-pack one layer's W (raw fp32 [K][64] global) into the LDS W buffer
// in A-fragment order (identical mapping to the r8-verified prep kernel):
//   LDS uint index u = (ks*2+mt)*256 + (lr*2+hi)*4 + j2
//   value = pack(W[k0*64+ch], W[(k0+1)*64+ch]), k0=ks*16+hi*8+j2*2, ch=mt*32+lr
// Thread mapping: idx = (kk, ch) with ch = idx&63 -> lane-coalesced reads.
// ---------------------------------------------------------------------------
template<int KS>
__device__ __forceinline__ void stage_w_direct(const float* __restrict__ W,
                                               char* __restrict__ wbuf) {
  unsigned int* d = (unsigned int*)wbuf;
  const int total = KS * 512;           // uints in this layer
  for (int idx = threadIdx.x; idx < total; idx += 256) {
    int ch = idx & 63;
    int kk = idx >> 6;                  // k-pair index, k0 = 2*kk
    int j2 = kk & 3, hi = (kk >> 2) & 1, ks = kk >> 3;
    int k0 = ks * 16 + hi * 8 + j2 * 2;
    int mt = ch >> 5, lr = ch & 31;
    int u = (((ks * 2 + mt) * 32 + lr) * 2 + hi) * 4 + j2;
    d[u] = cvt_pk_bf16(W[k0 * 64 + ch], W[(k0 + 1) * 64 + ch]);
  }
}

// ---------------------------------------------------------------------------
// One 32-row x 64-chan layer tile (verified r3..r21 math):
//   v_mfma_f32_32x32x16_bf16, D = W^T (A) x^T (B)
//     A: row=lane&31 (chan), k=(lane>>5)*8+j ; B: col=lane&31 (graph-row)
//     D: col=lane&31 (row), chan=(reg&3)+8*(reg>>2)+4*(lane>>5)
//   B-fragments preloaded (deep LDS pipeline), A-pairs JIT from the dense
//   per-layer LDS W buffer. LN(64) in-place + one shfl_xor(32).
//   Lanes lr>=vr produce garbage (contained: D-col==B-row) and are guarded.
// ---------------------------------------------------------------------------
template<int KS>
__device__ __forceinline__ void tile_layer(
    const char* __restrict__ wl,    // LDS W buffer (packed fragment order)
    char* __restrict__ xs, int xrow0, int vr,
    const float* __restrict__ Pb, const float* __restrict__ Pg,
    const float* __restrict__ Pn)
{
  const int lane = threadIdx.x & 63;
  const int lr   = lane & 31;
  const int hi   = lane >> 5;
  const int ch4  = hi * 4;
  const int br   = xrow0 + lr;
  const int wo   = (lr * 2 + hi) * 16;   // lane's byte offset within 64-frag group

  // preload all B-fragments (independent LDS reads, deep pipeline)
  bf16x8 bfr[KS];
#pragma unroll
  for (int ks = 0; ks < KS; ++ks)
    bfr[ks] = *(const bf16x8*)(xs + xswz(br, ks * 32 + hi * 16));

  f32x16 acc0 = zero16(), acc1 = zero16();
#pragma unroll
  for (int ks = 0; ks < KS; ++ks) {
    bf16x8 a0 = *(const bf16x8*)(wl + (ks * 2 + 0) * 1024 + wo);
    bf16x8 a1 = *(const bf16x8*)(wl + (ks * 2 + 1) * 1024 + wo);
    acc0 = __builtin_amdgcn_mfma_f32_32x32x16_bf16(a0, bfr[ks], acc0, 0, 0, 0);
    acc1 = __builtin_amdgcn_mfma_f32_32x32x16_bf16(a1, bfr[ks], acc1, 0, 0, 0);
  }

  // ---- bias (in place) + LayerNorm(64) ----
#pragma unroll
  for (int b = 0; b < 4; ++b) {
    float4 t0 = *(const float4*)&Pb[8 * b + ch4];
    float4 t1 = *(const float4*)&Pb[32 + 8 * b + ch4];
    acc0[4*b+0] += t0.x; acc0[4*b+1] += t0.y;
    acc0[4*b+2] += t0.z; acc0[4*b+3] += t0.w;
    acc1[4*b+0] += t1.x; acc1[4*b+1] += t1.y;
    acc1[4*b+2] += t1.z; acc1[4*b+3] += t1.w;
  }
  float s = 0.f, q = 0.f;
#pragma unroll
  for (int r = 0; r < 16; ++r) {
    s += acc0[r] + acc1[r];
    q = fmaf(acc0[r], acc0[r], q);
    q = fmaf(acc1[r], acc1[r], q);
  }
  s += __shfl_xor(s, 32);
  q += __shfl_xor(q, 32);
  float mu   = s * 0.015625f;
  float rstd = rsqrtf(fmaf(q, 0.015625f, -mu * mu) + 1e-5f);

  // ---- gamma/beta + ReLU, pack bf16, guarded swizzled write ----
#pragma unroll
  for (int b = 0; b < 4; ++b) {
    float4 g0 = *(const float4*)&Pg[8 * b + ch4];
    float4 n0 = *(const float4*)&Pn[8 * b + ch4];
    float4 g1 = *(const float4*)&Pg[32 + 8 * b + ch4];
    float4 n1 = *(const float4*)&Pn[32 + 8 * b + ch4];
    float h00 = fmaxf(0.f, fmaf((acc0[4*b+0] - mu) * rstd, g0.x, n0.x));
    float h01 = fmaxf(0.f, fmaf((acc0[4*b+1] - mu) * rstd, g0.y, n0.y));
    float h02 = fmaxf(0.f, fmaf((acc0[4*b+2] - mu) * rstd, g0.z, n0.z));
    float h03 = fmaxf(0.f, fmaf((acc0[4*b+3] - mu) * rstd, g0.w, n0.w));
    float h10 = fmaxf(0.f, fmaf((acc1[4*b+0] - mu) * rstd, g1.x, n1.x));
    float h11 = fmaxf(0.f, fmaf((acc1[4*b+1] - mu) * rstd, g1.y, n1.y));
    float h12 = fmaxf(0.f, fmaf((acc1[4*b+2] - mu) * rstd, g1.z, n1.z));
    float h13 = fmaxf(0.f, fmaf((acc1[4*b+3] - mu) * rstd, g1.w, n1.w));
    if (lr < vr) {
      uint2 u0; u0.x = cvt_pk_bf16(h00, h01); u0.y = cvt_pk_bf16(h02, h03);
      uint2 u1; u1.x = cvt_pk_bf16(h10, h11); u1.y = cvt_pk_bf16(h12, h13);
      *(uint2*)(xs + xswz(br, 16 * b + 8 * hi)) = u0;
      *(uint2*)(xs + xswz(br, 64 + 16 * b + 8 * hi)) = u1;
    }
  }
}

// map neighbor-max (top-2) for graph g / channel c, register row cache;
// h>=0 so bf16 bits compare as uint16
__device__ __forceinline__ void nmax_one(char* xs, int g, int c) {
  const int rb = g * NM_;
  unsigned int xv[NM_];
  unsigned int m1 = 0, m2 = 0;
#pragma unroll
  for (int n = 0; n < NM_; ++n) {
    xv[n] = *(const ushort_t*)(xs + xswz(rb + n, 2 * c));
    if (xv[n] > m1) { m2 = m1; m1 = xv[n]; } else if (xv[n] > m2) m2 = xv[n];
  }
#pragma unroll
  for (int n = 0; n < NM_; ++n)
    *(ushort_t*)(xs + xswz(rb + n, 128 + 2 * c)) =
        (ushort_t)((xv[n] == m1) ? m2 : m1);
}

// agent-pair neighbor-max: threads 0..127 -> (g=tid>>6 row base g*64, c)
__device__ __forceinline__ void nmax_agent2(char* xs) {
  const int tid = threadIdx.x;
  if (tid >= 128) return;
  const int g = tid >> 6, c = tid & 63;
  const int rb = g * 64;
  unsigned int m1 = 0, m2 = 0;
  for (int n = 0; n < NA_; ++n) {
    unsigned int x = *(const ushort_t*)(xs + xswz(rb + n, 2 * c));
    if (x > m1) { m2 = m1; m1 = x; } else if (x > m2) m2 = x;
  }
  for (int n = 0; n < NA_; ++n) {
    unsigned int x = *(const ushort_t*)(xs + xswz(rb + n, 2 * c));
    *(ushort_t*)(xs + xswz(rb + n, 128 + 2 * c)) =
        (ushort_t)((x == m1) ? m2 : m1);
  }
}

__device__ __forceinline__ void stage_params(
    const float* b0, const float* g0, const float* n0,
    const float* b1, const float* g1, const float* n1,
    const float* b2, const float* g2, const float* n2, float* Pp)
{
  const int tid = threadIdx.x;
  if (tid < 64) {
    Pp[      tid] = b0[tid]; Pp[ 64 + tid] = g0[tid]; Pp[128 + tid] = n0[tid];
    Pp[192 + tid] = b1[tid]; Pp[256 + tid] = g1[tid]; Pp[320 + tid] = n1[tid];
    Pp[384 + tid] = b2[tid]; Pp[448 + tid] = g2[tid]; Pp[512 + tid] = n2[tid];
  }
}

// ---------------------------------------------------------------------------
__global__ __launch_bounds__(256, 3) void subnet14(
    const float* __restrict__ agent, const float* __restrict__ mapf,
    const float* __restrict__ aw0, const float* __restrict__ ab0,
    const float* __restrict__ ag0, const float* __restrict__ an0,
    const float* __restrict__ aw1, const float* __restrict__ ab1,
    const float* __restrict__ ag1, const float* __restrict__ an1,
    const float* __restrict__ aw2, const float* __restrict__ ab2,
    const float* __restrict__ ag2, const float* __restrict__ an2,
    const float* __restrict__ mw0, const float* __restrict__ mb0,
    const float* __restrict__ mg0, const float* __restrict__ mn0,
    const float* __restrict__ mw1, const float* __restrict__ mb1,
    const float* __restrict__ mg1, const float* __restrict__ mn1,
    const float* __restrict__ mw2, const float* __restrict__ mb2,
    const float* __restrict__ mg2, const float* __restrict__ mn2,
    const float* __restrict__ fcw, const float* __restrict__ attnw,
    float* __restrict__ feats, float* __restrict__ waswad)
{
  __shared__ __align__(16) char smem[SMEMB];
  char*  xs   = smem;
  char*  wbuf = smem + XBYTES;
  float* Pp   = (float*)(smem + XBYTES + WBBYTES);
  const int tid = threadIdx.x;
  const int wid = tid >> 6;

  if (blockIdx.x == AGRID + MGRID) {
    // ---- was/wad block: waswad = fcw @ attnw[:128], fcw @ attnw[128:] ----
    const int lane = tid & 63;
    float a0 = attnw[lane],       a1 = attnw[64 + lane];
    float dd0 = attnw[128 + lane], dd1 = attnw[192 + lane];
    for (int r = wid; r < 128; r += 4) {
      float w0 = fcw[r * 128 + lane], w1 = fcw[r * 128 + 64 + lane];
      float s1 = w0 * a0 + w1 * a1;
      float s2 = w0 * dd0 + w1 * dd1;
#pragma unroll
      for (int off = 32; off; off >>= 1) {
        s1 += __shfl_xor(s1, off);
        s2 += __shfl_xor(s2, off);
      }
      if (lane == 0) { waswad[r] = s1; waswad[128 + r] = s2; }
    }
    return;
  }

  if (blockIdx.x < AGRID) {
    // ---- agent: 2 graphs/block at row bases 0,64 (4 tiles, valid
    // 32,17,32,17), barriers; graphs 2*bid and 2*bid+1 ----
    const int bid = blockIdx.x;
    const int vr = (wid & 1) ? 17 : 32;
    for (int i = tid; i < 2 * NA_ * 16; i += 256) {
      int g = i / (NA_ * 16);
      int rem = i - g * (NA_ * 16);
      int row = rem >> 4, k4 = (rem & 15) * 4;
      float4 v = *(const float4*)&agent[((size_t)(2 * bid + g) * NA_ + row) * 64 + k4];
      uint2 u; u.x = cvt_pk_bf16(v.x, v.y); u.y = cvt_pk_bf16(v.z, v.w);
      *(uint2*)(xs + xswz(g * 64 + row, 8 * (rem & 15))) = u;
    }
    stage_w_direct<4>(aw0, wbuf);
    stage_params(ab0, ag0, an0, ab1, ag1, an1, ab2, ag2, an2, Pp);
    __syncthreads();
    tile_layer<4>(wbuf, xs, wid * 32, vr, Pp, Pp + 64, Pp + 128);
    __syncthreads();
    nmax_agent2(xs);
    stage_w_direct<8>(aw1, wbuf);
    __syncthreads();
    tile_layer<8>(wbuf, xs, wid * 32, vr, Pp + 192, Pp + 256, Pp + 320);
    __syncthreads();
    nmax_agent2(xs);
    stage_w_direct<8>(aw2, wbuf);
    __syncthreads();
    tile_layer<8>(wbuf, xs, wid * 32, vr, Pp + 384, Pp + 448, Pp + 512);
    __syncthreads();
    if (tid < 128) {  // poly per (g,c): both halves = max over 49 nodes
      const int g = tid >> 6, c = tid & 63;
      const int rb = g * 64;
      unsigned int m1 = 0;
      for (int n = 0; n < NA_; ++n) {
        unsigned int x = *(const ushort_t*)(xs + xswz(rb + n, 2 * c));
        m1 = x > m1 ? x : m1;
      }
      float f = __uint_as_float(m1 << 16);
      size_t slot = (size_t)(2 * bid + g);
      feats[slot * 128 + c] = f;
      feats[slot * 128 + 64 + c] = f;
    }
  } else {
    // ---- map: 6 graphs dense-packed (114 rows, 4 tiles -> 4 busy waves);
    // tail block ng=2 (38 rows). W direct-packed per layer into LDS;
    // restage overlaps nmax (disjoint LDS regions). Pad-row garbage is
    // confined to lanes lr>=vr (write-guarded; LN lane pairs share lr). ----
    const int mbid = blockIdx.x - AGRID;
    const int gbase = mbid * 6;
    const int ng = (gbase + 6 <= P_ * B_) ? 6 : (P_ * B_ - gbase);
    const int rows = ng * NM_;
    int vr = rows - wid * 32;       // this wave's valid rows in its tile
    vr = vr > 32 ? 32 : vr;
    for (int i = tid; i < rows * 16; i += 256) {
      int row = i >> 4, k4 = (i & 15) * 4;
      float4 v = *(const float4*)&mapf[((size_t)gbase * NM_ + row) * 64 + k4];
      uint2 u; u.x = cvt_pk_bf16(v.x, v.y); u.y = cvt_pk_bf16(v.z, v.w);
      *(uint2*)(xs + xswz(row, 8 * (i & 15))) = u;
    }
    stage_w_direct<4>(mw0, wbuf);
    stage_params(mb0, mg0, mn0, mb1, mg1, mn1, mb2, mg2, mn2, Pp);
    __syncthreads();
    if (vr > 0) tile_layer<4>(wbuf, xs, wid * 32, vr, Pp, Pp + 64, Pp + 128);
    __syncthreads();
    for (int i = tid; i < ng * 64; i += 256) nmax_one(xs, i >> 6, i & 63);
    stage_w_direct<8>(mw1, wbuf);
    __syncthreads();
    if (vr > 0) tile_layer<8>(wbuf, xs, wid * 32, vr,
                              Pp + 192, Pp + 256, Pp + 320);
    __syncthreads();
    for (int i = tid; i < ng * 64; i += 256) nmax_one(xs, i >> 6, i & 63);
    stage_w_direct<8>(mw2, wbuf);
    __syncthreads();
    if (vr > 0) tile_layer<8>(wbuf, xs, wid * 32, vr,
                              Pp + 384, Pp + 448, Pp + 512);
    __syncthreads();
    for (int i = tid; i < ng * 64; i += 256) {  // poly per (g,c)
      const int g = i >> 6, c = i & 63;
      const int rb = g * NM_;
      unsigned int m1 = 0;
      for (int n = 0; n < NM_; ++n) {
        unsigned int x = *(const ushort_t*)(xs + xswz(rb + n, 2 * c));
        m1 = x > m1 ? x : m1;
      }
      float f = __uint_as_float(m1 << 16);
      size_t slot = (size_t)(B_ + gbase + g);
      feats[slot * 128 + c] = f;
      feats[slot * 128 + 64 + c] = f;
    }
  }
}

// ---------------------------------------------------------------------------
// GAT (only destination node 0 is read) + readout MLP. One block per batch b.
// si phase: 2 threads per dot (halved serial length); rest full-block split.
// ---------------------------------------------------------------------------
__global__ __launch_bounds__(256) void gat_kernel(
    const float* __restrict__ feats,    // [129][B][128] fp32
    const float* __restrict__ fcw,      // [128][128]
    const float* __restrict__ waswad,   // [256] precomputed
    const float* __restrict__ mlpw,     // [128][60]
    const float* __restrict__ mlpb,     // [60]
    float* __restrict__ out)            // [B][60]
{
  const int b = blockIdx.x, tid = threadIdx.x;
  __shared__ float was[128], wad[128];
  __shared__ float si[130];
  __shared__ float alpha[128], red[8];
  __shared__ float up[2][128], ubuf[128], hgp[2][128], op[2][60];

  if (tid < 128) { was[tid] = waswad[tid]; wad[tid] = waswad[128 + tid]; }
  __syncthreads();

  {  // si[1..128]: 2 threads per dot (idx = tid>>1, halves of k)
    const int idx = tid >> 1, half = tid & 1;
    const float* fr = feats + ((size_t)(idx + 1) * B_ + b) * 128 + half * 64;
    const float* wa = was + half * 64;
    float s = 0.f;
    for (int k = 0; k < 64; k += 4) {
      float4 f = *(const float4*)&fr[k];
      s += f.x * wa[k] + f.y * wa[k + 1] + f.z * wa[k + 2] + f.w * wa[k + 3];
    }
    s += __shfl_xor(s, 1);
    if (half == 0) si[idx + 1] = s;
    if (tid < 2) {  // d0 = feats[node 0][b] . wad (threads 0,1 split k)
      const float* f0 = feats + (size_t)b * 128 + tid * 64;
      const float* wd = wad + tid * 64;
      float s2 = 0.f;
      for (int k = 0; k < 64; k += 4) {
        float4 f = *(const float4*)&f0[k];
        s2 += f.x * wd[k] + f.y * wd[k + 1] + f.z * wd[k + 2] + f.w * wd[k + 3];
      }
      s2 += __shfl_xor(s2, 1);
      if (tid == 0) si[129] = s2;
    }
  }
  __syncthreads();

  float d0 = si[129];
  float e = -3.4e38f;
  if (tid < 128) {
    float x = si[tid + 1] + d0;
    e = (x > 0.f) ? x : 0.01f * x;
  }
  float m = e;
#pragma unroll
  for (int off = 32; off; off >>= 1) m = fmaxf(m, __shfl_xor(m, off));
  if ((tid & 63) == 0) red[tid >> 6] = m;
  __syncthreads();
  float mx = fmaxf(red[0], red[1]);
  float p = (tid < 128) ? expf(e - mx) : 0.f;
  float s = p;
#pragma unroll
  for (int off = 32; off; off >>= 1) s += __shfl_xor(s, off);
  if ((tid & 63) == 0) red[4 + (tid >> 6)] = s;
  __syncthreads();
  float denom = red[4] + red[5];
  if (tid < 128) alpha[tid] = p / denom;
  __syncthreads();

  {  // u = sum_t alpha_t feats[t+1][b][:]  — split t over two halves
    const int c = tid & 127, h = tid >> 7;
    const float* fb = feats + ((size_t)(h * 64 + 1) * B_ + b) * 128 + c;
    float u = 0.f;
    for (int t = 0; t < 64; ++t)
      u += alpha[h * 64 + t] * fb[(size_t)t * B_ * 128];
    up[h][c] = u;
  }
  __syncthreads();
  if (tid < 128) ubuf[tid] = up[0][tid] + up[1][tid];
  __syncthreads();

  {  // hg = ubuf @ fcw — split k over two halves
    const int c = tid & 127, h = tid >> 7;
    float sacc = 0.f;
    for (int k = 0; k < 64; ++k)
      sacc += ubuf[h * 64 + k] * fcw[(h * 64 + k) * 128 + c];
    hgp[h][c] = sacc;
  }
  __syncthreads();

  if (tid < 120) {  // out = hg @ mlpw + mlpb — split c over two halves
    const int o = tid % 60, h = tid / 60;
    float sacc = 0.f;
    for (int c = 0; c < 64; ++c)
      sacc += (hgp[0][h * 64 + c] + hgp[1][h * 64 + c]) * mlpw[(h * 64 + c) * OUT_ + o];
    op[h][o] = sacc;
  }
  __syncthreads();
  if (tid < OUT_) out[b * OUT_ + tid] = mlpb[tid] + op[0][tid] + op[1][tid];
}

// ---------------------------------------------------------------------------
extern "C" void kernel_launch(void* const* d_in, const int* in_sizes, int n_in,
                              void* d_out, int out_size, void* d_ws, size_t ws_size,
                              hipStream_t stream) {
  (void)in_sizes; (void)n_in; (void)out_size; (void)ws_size;

  const float* agent = (const float*)d_in[0];   // [B][NA][64]
  const float* mapf  = (const float*)d_in[1];   // [P][B][NM][64]
  // d_in[2] = map_mask (all ones, unused)

  const float* aw0 = (const float*)d_in[3];
  const float* ab0 = (const float*)d_in[4];
  const float* ag0 = (const float*)d_in[5];
  const float* an0 = (const float*)d_in[6];
  const float* aw1 = (const float*)d_in[7];
  const float* ab1 = (const float*)d_in[8];
  const float* ag1 = (const float*)d_in[9];
  const float* an1 = (const float*)d_in[10];
  const float* aw2 = (const float*)d_in[11];
  const float* ab2 = (const float*)d_in[12];
  const float* ag2 = (const float*)d_in[13];
  const float* an2 = (const float*)d_in[14];

  const float* mw0 = (const float*)d_in[15];
  const float* mb0 = (const float*)d_in[16];
  const float* mg0 = (const float*)d_in[17];
  const float* mn0 = (const float*)d_in[18];
  const float* mw1 = (const float*)d_in[19];
  const float* mb1 = (const float*)d_in[20];
  const float* mg1 = (const float*)d_in[21];
  const float* mn1 = (const float*)d_in[22];
  const float* mw2 = (const float*)d_in[23];
  const float* mb2 = (const float*)d_in[24];
  const float* mg2 = (const float*)d_in[25];
  const float* mn2 = (const float*)d_in[26];

  const float* fcw   = (const float*)d_in[27];
  const float* attnw = (const float*)d_in[28];
  const float* mlpw  = (const float*)d_in[29];
  const float* mlpb  = (const float*)d_in[30];

  float* feats = (float*)d_ws;
  float* waswad = (float*)((char*)d_ws + FEATS_BYTES);
  float* out = (float*)d_out;

  // 1) fused agent(32) + map(1366) + waswad(1) subnet; W direct-packed
  //    per block into LDS (prep kernel eliminated)
  subnet14<<<AGRID + MGRID + 1, 256, 0, stream>>>(
      agent, mapf,
      aw0, ab0, ag0, an0, aw1, ab1, ag1, an1, aw2, ab2, ag2, an2,
      mw0, mb0, mg0, mn0, mw1, mb1, mg1, mn1, mw2, mb2, mg2, mn2,
      fcw, attnw, feats, waswad);

  // 2) GAT column-0 + MLP readout (parallel si, full-block loops)
  gat_kernel<<<B_, 256, 0, stream>>>(feats, fcw, waswad, mlpw, mlpb, out);
}

// Round 23
// 55.117 us; speedup vs baseline: 1.0603x; 1.0139x over previous
//
#include <hip/hip_runtime.h>
#include <stdint.h>

// Problem dims (VectorNet): B=64, NA=49, NM=19, P=128, IN=64, H=64, OUT=60, H2=128
#define B_    64
#define NA_   49
#define NM_   19
#define P_    128
#define OUT_  60
#define AGRID 32          // agent: 2 graphs/block (row bases 0,64; 4 tiles)
#define MGRID 1366        // map: 6 graphs/block (114 rows, 4 tiles); tail ng=2
// X tile: 128 rows x 128 ch bf16, XOR-swizzled, row stride 256B
#define XR     128
#define XBYTES (XR * 256)            // 32768
#define WBBYTES 16384                // W LDS buffer (largest layer)
#define PBYTES (9 * 64 * 4)          // 768
#define SMEMB  (XBYTES + WBBYTES + PBYTES)   // 49920 -> 3 blocks/CU
// d_ws layout: feats | was/wad
#define FEATS_BYTES (129 * 64 * 128 * 4)     // 4227072

typedef __bf16 bf16x8 __attribute__((ext_vector_type(8)));
typedef float  f32x16 __attribute__((ext_vector_type(16)));
typedef unsigned short ushort_t;

__device__ __forceinline__ unsigned int cvt_pk_bf16(float lo, float hi) {
  unsigned int r;
  asm("v_cvt_pk_bf16_f32 %0, %1, %2" : "=v"(r) : "v"(lo), "v"(hi));
  return r;
}

__device__ __forceinline__ f32x16 zero16() {
  f32x16 z;
#pragma unroll
  for (int i = 0; i < 16; ++i) z[i] = 0.f;
  return z;
}

// swizzled X address: row stride 256B, byte ^= (row&7)<<4
__device__ __forceinline__ int xswz(int row, int byteoff) {
  return row * 256 + (byteoff ^ ((row & 7) << 4));
}

// fragment-slot swizzle within each 1KB W group (involution; spreads the
// stride-2 slot writes of stage_w_direct across all banks; reads stay dense)
__device__ __forceinline__ int fswz(int s) {
  return s ^ ((s >> 3) & 7);
}

// ---------------------------------------------------------------------------
// Direct-pack one layer's W (raw fp32 [K][64] global) into the LDS W buffer
// in A-fragment order (r8-verified mapping + fswz slot permutation):
//   LDS uint index u = (ks*2+mt)*256 + fswz(lr*2+hi)*4 + j2
//   value = pack(W[k0*64+ch], W[(k0+1)*64+ch]), k0=ks*16+hi*8+j2*2, ch=mt*32+lr
// Thread mapping: idx = (kk, ch), ch = idx&63 -> lane-coalesced global reads;
// fswz makes the LDS writes bank-conflict-free (r22 lesson: unswizzled
// stride-8 writes were an 8-way conflict, +3.1M conflict cycles).
// ---------------------------------------------------------------------------
template<int KS>
__device__ __forceinline__ void stage_w_direct(const float* __restrict__ W,
                                               char* __restrict__ wbuf) {
  unsigned int* d = (unsigned int*)wbuf;
  const int total = KS * 512;           // uints in this layer
  for (int idx = threadIdx.x; idx < total; idx += 256) {
    int ch = idx & 63;
    int kk = idx >> 6;                  // k-pair index, k0 = 2*kk
    int j2 = kk & 3, hi = (kk >> 2) & 1, ks = kk >> 3;
    int k0 = ks * 16 + hi * 8 + j2 * 2;
    int mt = ch >> 5, lr = ch & 31;
    int u = ((ks * 2 + mt) * 64 + fswz(lr * 2 + hi)) * 4 + j2;
    d[u] = cvt_pk_bf16(W[k0 * 64 + ch], W[(k0 + 1) * 64 + ch]);
  }
}

// ---------------------------------------------------------------------------
// One 32-row x 64-chan layer tile (verified r3..r22 math):
//   v_mfma_f32_32x32x16_bf16, D = W^T (A) x^T (B)
//     A: row=lane&31 (chan), k=(lane>>5)*8+j ; B: col=lane&31 (graph-row)
//     D: col=lane&31 (row), chan=(reg&3)+8*(reg>>2)+4*(lane>>5)
//   B-fragments preloaded (deep LDS pipeline), A-pairs JIT from the dense
//   per-layer LDS W buffer (fswz slot layout). LN(64) in-place + shfl_xor(32).
//   Lanes lr>=vr produce garbage (contained: D-col==B-row) and are guarded.
// ---------------------------------------------------------------------------
template<int KS>
__device__ __forceinline__ void tile_layer(
    const char* __restrict__ wl,    // LDS W buffer (packed fragment order)
    char* __restrict__ xs, int xrow0, int vr,
    const float* __restrict__ Pb, const float* __restrict__ Pg,
    const float* __restrict__ Pn)
{
  const int lane = threadIdx.x & 63;
  const int lr   = lane & 31;
  const int hi   = lane >> 5;
  const int ch4  = hi * 4;
  const int br   = xrow0 + lr;
  const int wo   = fswz(lr * 2 + hi) * 16;   // lane's byte offset in 1KB group

  // preload all B-fragments (independent LDS reads, deep pipeline)
  bf16x8 bfr[KS];
#pragma unroll
  for (int ks = 0; ks < KS; ++ks)
    bfr[ks] = *(const bf16x8*)(xs + xswz(br, ks * 32 + hi * 16));

  f32x16 acc0 = zero16(), acc1 = zero16();
#pragma unroll
  for (int ks = 0; ks < KS; ++ks) {
    bf16x8 a0 = *(const bf16x8*)(wl + (ks * 2 + 0) * 1024 + wo);
    bf16x8 a1 = *(const bf16x8*)(wl + (ks * 2 + 1) * 1024 + wo);
    acc0 = __builtin_amdgcn_mfma_f32_32x32x16_bf16(a0, bfr[ks], acc0, 0, 0, 0);
    acc1 = __builtin_amdgcn_mfma_f32_32x32x16_bf16(a1, bfr[ks], acc1, 0, 0, 0);
  }

  // ---- bias (in place) + LayerNorm(64) ----
#pragma unroll
  for (int b = 0; b < 4; ++b) {
    float4 t0 = *(const float4*)&Pb[8 * b + ch4];
    float4 t1 = *(const float4*)&Pb[32 + 8 * b + ch4];
    acc0[4*b+0] += t0.x; acc0[4*b+1] += t0.y;
    acc0[4*b+2] += t0.z; acc0[4*b+3] += t0.w;
    acc1[4*b+0] += t1.x; acc1[4*b+1] += t1.y;
    acc1[4*b+2] += t1.z; acc1[4*b+3] += t1.w;
  }
  float s = 0.f, q = 0.f;
#pragma unroll
  for (int r = 0; r < 16; ++r) {
    s += acc0[r] + acc1[r];
    q = fmaf(acc0[r], acc0[r], q);
    q = fmaf(acc1[r], acc1[r], q);
  }
  s += __shfl_xor(s, 32);
  q += __shfl_xor(q, 32);
  float mu   = s * 0.015625f;
  float rstd = rsqrtf(fmaf(q, 0.015625f, -mu * mu) + 1e-5f);

  // ---- gamma/beta + ReLU, pack bf16, guarded swizzled write ----
#pragma unroll
  for (int b = 0; b < 4; ++b) {
    float4 g0 = *(const float4*)&Pg[8 * b + ch4];
    float4 n0 = *(const float4*)&Pn[8 * b + ch4];
    float4 g1 = *(const float4*)&Pg[32 + 8 * b + ch4];
    float4 n1 = *(const float4*)&Pn[32 + 8 * b + ch4];
    float h00 = fmaxf(0.f, fmaf((acc0[4*b+0] - mu) * rstd, g0.x, n0.x));
    float h01 = fmaxf(0.f, fmaf((acc0[4*b+1] - mu) * rstd, g0.y, n0.y));
    float h02 = fmaxf(0.f, fmaf((acc0[4*b+2] - mu) * rstd, g0.z, n0.z));
    float h03 = fmaxf(0.f, fmaf((acc0[4*b+3] - mu) * rstd, g0.w, n0.w));
    float h10 = fmaxf(0.f, fmaf((acc1[4*b+0] - mu) * rstd, g1.x, n1.x));
    float h11 = fmaxf(0.f, fmaf((acc1[4*b+1] - mu) * rstd, g1.y, n1.y));
    float h12 = fmaxf(0.f, fmaf((acc1[4*b+2] - mu) * rstd, g1.z, n1.z));
    float h13 = fmaxf(0.f, fmaf((acc1[4*b+3] - mu) * rstd, g1.w, n1.w));
    if (lr < vr) {
      uint2 u0; u0.x = cvt_pk_bf16(h00, h01); u0.y = cvt_pk_bf16(h02, h03);
      uint2 u1; u1.x = cvt_pk_bf16(h10, h11); u1.y = cvt_pk_bf16(h12, h13);
      *(uint2*)(xs + xswz(br, 16 * b + 8 * hi)) = u0;
      *(uint2*)(xs + xswz(br, 64 + 16 * b + 8 * hi)) = u1;
    }
  }
}

// map neighbor-max (top-2) for graph g / channel c, register row cache;
// h>=0 so bf16 bits compare as uint16
__device__ __forceinline__ void nmax_one(char* xs, int g, int c) {
  const int rb = g * NM_;
  unsigned int xv[NM_];
  unsigned int m1 = 0, m2 = 0;
#pragma unroll
  for (int n = 0; n < NM_; ++n) {
    xv[n] = *(const ushort_t*)(xs + xswz(rb + n, 2 * c));
    if (xv[n] > m1) { m2 = m1; m1 = xv[n]; } else if (xv[n] > m2) m2 = xv[n];
  }
#pragma unroll
  for (int n = 0; n < NM_; ++n)
    *(ushort_t*)(xs + xswz(rb + n, 128 + 2 * c)) =
        (ushort_t)((xv[n] == m1) ? m2 : m1);
}

// agent-pair neighbor-max: threads 0..127 -> (g=tid>>6 row base g*64, c)
__device__ __forceinline__ void nmax_agent2(char* xs) {
  const int tid = threadIdx.x;
  if (tid >= 128) return;
  const int g = tid >> 6, c = tid & 63;
  const int rb = g * 64;
  unsigned int m1 = 0, m2 = 0;
  for (int n = 0; n < NA_; ++n) {
    unsigned int x = *(const ushort_t*)(xs + xswz(rb + n, 2 * c));
    if (x > m1) { m2 = m1; m1 = x; } else if (x > m2) m2 = x;
  }
  for (int n = 0; n < NA_; ++n) {
    unsigned int x = *(const ushort_t*)(xs + xswz(rb + n, 2 * c));
    *(ushort_t*)(xs + xswz(rb + n, 128 + 2 * c)) =
        (ushort_t)((x == m1) ? m2 : m1);
  }
}

__device__ __forceinline__ void stage_params(
    const float* b0, const float* g0, const float* n0,
    const float* b1, const float* g1, const float* n1,
    const float* b2, const float* g2, const float* n2, float* Pp)
{
  const int tid = threadIdx.x;
  if (tid < 64) {
    Pp[      tid] = b0[tid]; Pp[ 64 + tid] = g0[tid]; Pp[128 + tid] = n0[tid];
    Pp[192 + tid] = b1[tid]; Pp[256 + tid] = g1[tid]; Pp[320 + tid] = n1[tid];
    Pp[384 + tid] = b2[tid]; Pp[448 + tid] = g2[tid]; Pp[512 + tid] = n2[tid];
  }
}

// ---------------------------------------------------------------------------
__global__ __launch_bounds__(256, 3) void subnet15(
    const float* __restrict__ agent, const float* __restrict__ mapf,
    const float* __restrict__ aw0, const float* __restrict__ ab0,
    const float* __restrict__ ag0, const float* __restrict__ an0,
    const float* __restrict__ aw1, const float* __restrict__ ab1,
    const float* __restrict__ ag1, const float* __restrict__ an1,
    const float* __restrict__ aw2, const float* __restrict__ ab2,
    const float* __restrict__ ag2, const float* __restrict__ an2,
    const float* __restrict__ mw0, const float* __restrict__ mb0,
    const float* __restrict__ mg0, const float* __restrict__ mn0,
    const float* __restrict__ mw1, const float* __restrict__ mb1,
    const float* __restrict__ mg1, const float* __restrict__ mn1,
    const float* __restrict__ mw2, const float* __restrict__ mb2,
    const float* __restrict__ mg2, const float* __restrict__ mn2,
    const float* __restrict__ fcw, const float* __restrict__ attnw,
    float* __restrict__ feats, float* __restrict__ waswad)
{
  __shared__ __align__(16) char smem[SMEMB];
  char*  xs   = smem;
  char*  wbuf = smem + XBYTES;
  float* Pp   = (float*)(smem + XBYTES + WBBYTES);
  const int tid = threadIdx.x;
  const int wid = tid >> 6;

  if (blockIdx.x == AGRID + MGRID) {
    // ---- was/wad block: waswad = fcw @ attnw[:128], fcw @ attnw[128:] ----
    const int lane = tid & 63;
    float a0 = attnw[lane],       a1 = attnw[64 + lane];
    float dd0 = attnw[128 + lane], dd1 = attnw[192 + lane];
    for (int r = wid; r < 128; r += 4) {
      float w0 = fcw[r * 128 + lane], w1 = fcw[r * 128 + 64 + lane];
      float s1 = w0 * a0 + w1 * a1;
      float s2 = w0 * dd0 + w1 * dd1;
#pragma unroll
      for (int off = 32; off; off >>= 1) {
        s1 += __shfl_xor(s1, off);
        s2 += __shfl_xor(s2, off);
      }
      if (lane == 0) { waswad[r] = s1; waswad[128 + r] = s2; }
    }
    return;
  }

  if (blockIdx.x < AGRID) {
    // ---- agent: 2 graphs/block at row bases 0,64 (4 tiles, valid
    // 32,17,32,17), barriers; graphs 2*bid and 2*bid+1 ----
    const int bid = blockIdx.x;
    const int vr = (wid & 1) ? 17 : 32;
    for (int i = tid; i < 2 * NA_ * 16; i += 256) {
      int g = i / (NA_ * 16);
      int rem = i - g * (NA_ * 16);
      int row = rem >> 4, k4 = (rem & 15) * 4;
      float4 v = *(const float4*)&agent[((size_t)(2 * bid + g) * NA_ + row) * 64 + k4];
      uint2 u; u.x = cvt_pk_bf16(v.x, v.y); u.y = cvt_pk_bf16(v.z, v.w);
      *(uint2*)(xs + xswz(g * 64 + row, 8 * (rem & 15))) = u;
    }
    stage_w_direct<4>(aw0, wbuf);
    stage_params(ab0, ag0, an0, ab1, ag1, an1, ab2, ag2, an2, Pp);
    __syncthreads();
    tile_layer<4>(wbuf, xs, wid * 32, vr, Pp, Pp + 64, Pp + 128);
    __syncthreads();
    nmax_agent2(xs);
    stage_w_direct<8>(aw1, wbuf);
    __syncthreads();
    tile_layer<8>(wbuf, xs, wid * 32, vr, Pp + 192, Pp + 256, Pp + 320);
    __syncthreads();
    nmax_agent2(xs);
    stage_w_direct<8>(aw2, wbuf);
    __syncthreads();
    tile_layer<8>(wbuf, xs, wid * 32, vr, Pp + 384, Pp + 448, Pp + 512);
    __syncthreads();
    if (tid < 128) {  // poly per (g,c): both halves = max over 49 nodes
      const int g = tid >> 6, c = tid & 63;
      const int rb = g * 64;
      unsigned int m1 = 0;
      for (int n = 0; n < NA_; ++n) {
        unsigned int x = *(const ushort_t*)(xs + xswz(rb + n, 2 * c));
        m1 = x > m1 ? x : m1;
      }
      float f = __uint_as_float(m1 << 16);
      size_t slot = (size_t)(2 * bid + g);
      feats[slot * 128 + c] = f;
      feats[slot * 128 + 64 + c] = f;
    }
  } else {
    // ---- map: 6 graphs dense-packed (114 rows, 4 tiles -> 4 busy waves);
    // tail block ng=2 (38 rows). W direct-packed per layer into LDS;
    // restage overlaps nmax (disjoint LDS regions). Pad-row garbage is
    // confined to lanes lr>=vr (write-guarded; LN lane pairs share lr). ----
    const int mbid = blockIdx.x - AGRID;
    const int gbase = mbid * 6;
    const int ng = (gbase + 6 <= P_ * B_) ? 6 : (P_ * B_ - gbase);
    const int rows = ng * NM_;
    int vr = rows - wid * 32;       // this wave's valid rows in its tile
    vr = vr > 32 ? 32 : vr;
    for (int i = tid; i < rows * 16; i += 256) {
      int row = i >> 4, k4 = (i & 15) * 4;
      float4 v = *(const float4*)&mapf[((size_t)gbase * NM_ + row) * 64 + k4];
      uint2 u; u.x = cvt_pk_bf16(v.x, v.y); u.y = cvt_pk_bf16(v.z, v.w);
      *(uint2*)(xs + xswz(row, 8 * (i & 15))) = u;
    }
    stage_w_direct<4>(mw0, wbuf);
    stage_params(mb0, mg0, mn0, mb1, mg1, mn1, mb2, mg2, mn2, Pp);
    __syncthreads();
    if (vr > 0) tile_layer<4>(wbuf, xs, wid * 32, vr, Pp, Pp + 64, Pp + 128);
    __syncthreads();
    for (int i = tid; i < ng * 64; i += 256) nmax_one(xs, i >> 6, i & 63);
    stage_w_direct<8>(mw1, wbuf);
    __syncthreads();
    if (vr > 0) tile_layer<8>(wbuf, xs, wid * 32, vr,
                              Pp + 192, Pp + 256, Pp + 320);
    __syncthreads();
    for (int i = tid; i < ng * 64; i += 256) nmax_one(xs, i >> 6, i & 63);
    stage_w_direct<8>(mw2, wbuf);
    __syncthreads();
    if (vr > 0) tile_layer<8>(wbuf, xs, wid * 32, vr,
                              Pp + 384, Pp + 448, Pp + 512);
    __syncthreads();
    for (int i = tid; i < ng * 64; i += 256) {  // poly per (g,c)
      const int g = i >> 6, c = i & 63;
      const int rb = g * NM_;
      unsigned int m1 = 0;
      for (int n = 0; n < NM_; ++n) {
        unsigned int x = *(const ushort_t*)(xs + xswz(rb + n, 2 * c));
        m1 = x > m1 ? x : m1;
      }
      float f = __uint_as_float(m1 << 16);
      size_t slot = (size_t)(B_ + gbase + g);
      feats[slot * 128 + c] = f;
      feats[slot * 128 + 64 + c] = f;
    }
  }
}

// ---------------------------------------------------------------------------
// GAT (only destination node 0 is read) + readout MLP. One block per batch b.
// si phase: 2 threads per dot (halved serial length); rest full-block split.
// ---------------------------------------------------------------------------
__global__ __launch_bounds__(256) void gat_kernel(
    const float* __restrict__ feats,    // [129][B][128] fp32
    const float* __restrict__ fcw,      // [128][128]
    const float* __restrict__ waswad,   // [256] precomputed
    const float* __restrict__ mlpw,     // [128][60]
    const float* __restrict__ mlpb,     // [60]
    float* __restrict__ out)            // [B][60]
{
  const int b = blockIdx.x, tid = threadIdx.x;
  __shared__ float was[128], wad[128];
  __shared__ float si[130];
  __shared__ float alpha[128], red[8];
  __shared__ float up[2][128], ubuf[128], hgp[2][128], op[2][60];

  if (tid < 128) { was[tid] = waswad[tid]; wad[tid] = waswad[128 + tid]; }
  __syncthreads();

  {  // si[1..128]: 2 threads per dot (idx = tid>>1, halves of k)
    const int idx = tid >> 1, half = tid & 1;
    const float* fr = feats + ((size_t)(idx + 1) * B_ + b) * 128 + half * 64;
    const float* wa = was + half * 64;
    float s = 0.f;
    for (int k = 0; k < 64; k += 4) {
      float4 f = *(const float4*)&fr[k];
      s += f.x * wa[k] + f.y * wa[k + 1] + f.z * wa[k + 2] + f.w * wa[k + 3];
    }
    s += __shfl_xor(s, 1);
    if (half == 0) si[idx + 1] = s;
    if (tid < 2) {  // d0 = feats[node 0][b] . wad (threads 0,1 split k)
      const float* f0 = feats + (size_t)b * 128 + tid * 64;
      const float* wd = wad + tid * 64;
      float s2 = 0.f;
      for (int k = 0; k < 64; k += 4) {
        float4 f = *(const float4*)&f0[k];
        s2 += f.x * wd[k] + f.y * wd[k + 1] + f.z * wd[k + 2] + f.w * wd[k + 3];
      }
      s2 += __shfl_xor(s2, 1);
      if (tid == 0) si[129] = s2;
    }
  }
  __syncthreads();

  float d0 = si[129];
  float e = -3.4e38f;
  if (tid < 128) {
    float x = si[tid + 1] + d0;
    e = (x > 0.f) ? x : 0.01f * x;
  }
  float m = e;
#pragma unroll
  for (int off = 32; off; off >>= 1) m = fmaxf(m, __shfl_xor(m, off));
  if ((tid & 63) == 0) red[tid >> 6] = m;
  __syncthreads();
  float mx = fmaxf(red[0], red[1]);
  float p = (tid < 128) ? expf(e - mx) : 0.f;
  float s = p;
#pragma unroll
  for (int off = 32; off; off >>= 1) s += __shfl_xor(s, off);
  if ((tid & 63) == 0) red[4 + (tid >> 6)] = s;
  __syncthreads();
  float denom = red[4] + red[5];
  if (tid < 128) alpha[tid] = p / denom;
  __syncthreads();

  {  // u = sum_t alpha_t feats[t+1][b][:]  — split t over two halves
    const int c = tid & 127, h = tid >> 7;
    const float* fb = feats + ((size_t)(h * 64 + 1) * B_ + b) * 128 + c;
    float u = 0.f;
    for (int t = 0; t < 64; ++t)
      u += alpha[h * 64 + t] * fb[(size_t)t * B_ * 128];
    up[h][c] = u;
  }
  __syncthreads();
  if (tid < 128) ubuf[tid] = up[0][tid] + up[1][tid];
  __syncthreads();

  {  // hg = ubuf @ fcw — split k over two halves
    const int c = tid & 127, h = tid >> 7;
    float sacc = 0.f;
    for (int k = 0; k < 64; ++k)
      sacc += ubuf[h * 64 + k] * fcw[(h * 64 + k) * 128 + c];
    hgp[h][c] = sacc;
  }
  __syncthreads();

  if (tid < 120) {  // out = hg @ mlpw + mlpb — split c over two halves
    const int o = tid % 60, h = tid / 60;
    float sacc = 0.f;
    for (int c = 0; c < 64; ++c)
      sacc += (hgp[0][h * 64 + c] + hgp[1][h * 64 + c]) * mlpw[(h * 64 + c) * OUT_ + o];
    op[h][o] = sacc;
  }
  __syncthreads();
  if (tid < OUT_) out[b * OUT_ + tid] = mlpb[tid] + op[0][tid] + op[1][tid];
}

// ---------------------------------------------------------------------------
extern "C" void kernel_launch(void* const* d_in, const int* in_sizes, int n_in,
                              void* d_out, int out_size, void* d_ws, size_t ws_size,
                              hipStream_t stream) {
  (void)in_sizes; (void)n_in; (void)out_size; (void)ws_size;

  const float* agent = (const float*)d_in[0];   // [B][NA][64]
  const float* mapf  = (const float*)d_in[1];   // [P][B][NM][64]
  // d_in[2] = map_mask (all ones, unused)

  const float* aw0 = (const float*)d_in[3];
  const float* ab0 = (const float*)d_in[4];
  const float* ag0 = (const float*)d_in[5];
  const float* an0 = (const float*)d_in[6];
  const float* aw1 = (const float*)d_in[7];
  const float* ab1 = (const float*)d_in[8];
  const float* ag1 = (const float*)d_in[9];
  const float* an1 = (const float*)d_in[10];
  const float* aw2 = (const float*)d_in[11];
  const float* ab2 = (const float*)d_in[12];
  const float* ag2 = (const float*)d_in[13];
  const float* an2 = (const float*)d_in[14];

  const float* mw0 = (const float*)d_in[15];
  const float* mb0 = (const float*)d_in[16];
  const float* mg0 = (const float*)d_in[17];
  const float* mn0 = (const float*)d_in[18];
  const float* mw1 = (const float*)d_in[19];
  const float* mb1 = (const float*)d_in[20];
  const float* mg1 = (const float*)d_in[21];
  const float* mn1 = (const float*)d_in[22];
  const float* mw2 = (const float*)d_in[23];
  const float* mb2 = (const float*)d_in[24];
  const float* mg2 = (const float*)d_in[25];
  const float* mn2 = (const float*)d_in[26];

  const float* fcw   = (const float*)d_in[27];
  const float* attnw = (const float*)d_in[28];
  const float* mlpw  = (const float*)d_in[29];
  const float* mlpb  = (const float*)d_in[30];

  float* feats = (float*)d_ws;
  float* waswad = (float*)((char*)d_ws + FEATS_BYTES);
  float* out = (float*)d_out;

  // 1) fused agent(32) + map(1366) + waswad(1) subnet; W direct-packed
  //    per block into LDS with conflict-free fswz slot layout
  subnet15<<<AGRID + MGRID + 1, 256, 0, stream>>>(
      agent, mapf,
      aw0, ab0, ag0, an0, aw1, ab1, ag1, an1, aw2, ab2, ag2, an2,
      mw0, mb0, mg0, mn0, mw1, mb1, mg1, mn1, mw2, mb2, mg2, mn2,
      fcw, attnw, feats, waswad);

  // 2) GAT column-0 + MLP readout (parallel si, full-block loops)
  gat_kernel<<<B_, 256, 0, stream>>>(feats, fcw, waswad, mlpw, mlpb, out);
}

// Round 24
// 51.085 us; speedup vs baseline: 1.1439x; 1.0789x over previous
//
#include <hip/hip_runtime.h>
#include <stdint.h>

// Problem dims (VectorNet): B=64, NA=49, NM=19, P=128, IN=64, H=64, OUT=60, H2=128
#define B_    64
#define NA_   49
#define NM_   19
#define P_    128
#define OUT_  60
#define AGRID 32          // agent: 2 graphs/block (row bases 0,64; 4 tiles)
#define MGRID 1366        // map: 6 graphs/block (114 rows, 4 tiles); tail ng=2
// X tile: 128 rows x 128 ch bf16, XOR-swizzled, row stride 256B
#define XR     128
#define XBYTES (XR * 256)            // 32768
#define WBBYTES 16384                // W LDS buffer (largest layer)
#define PBYTES (9 * 64 * 4)          // 768
#define SMEMB  (XBYTES + WBBYTES + PBYTES)   // 49920 -> 3 blocks/CU
// d_ws layout: feats | was/wad
#define FEATS_BYTES (129 * 64 * 128 * 4)     // 4227072

typedef __bf16 bf16x8 __attribute__((ext_vector_type(8)));
typedef float  f32x16 __attribute__((ext_vector_type(16)));
typedef unsigned short ushort_t;

__device__ __forceinline__ unsigned int cvt_pk_bf16(float lo, float hi) {
  unsigned int r;
  asm("v_cvt_pk_bf16_f32 %0, %1, %2" : "=v"(r) : "v"(lo), "v"(hi));
  return r;
}

__device__ __forceinline__ f32x16 zero16() {
  f32x16 z;
#pragma unroll
  for (int i = 0; i < 16; ++i) z[i] = 0.f;
  return z;
}

// swizzled X address: row stride 256B, byte ^= (row&7)<<4
__device__ __forceinline__ int xswz(int row, int byteoff) {
  return row * 256 + (byteoff ^ ((row & 7) << 4));
}

// ---------------------------------------------------------------------------
// Direct-pack one layer's W (raw fp32 [K][64] global) into the LDS W buffer,
// dense r8/r21 fragment layout. One thread per 16B FRAGMENT, single uint4
// LDS write -> bijective 16B slots = bank-conflict-free (r23 lesson: per-
// dword writes can reach at best 8 banks since j2 is wave-constant).
//   fragment f = g*64 + s, g = ks*2+mt, s = lr*2+hi
//   holds k = ks*16+hi*8+(0..7), ch = mt*32+lr; uint j2 = pack(k0+2j2, k0+2j2+1)
// ---------------------------------------------------------------------------
template<int KS>
__device__ __forceinline__ void stage_w_direct(const float* __restrict__ W,
                                               char* __restrict__ wbuf) {
  const int nfrag = KS * 128;
  for (int f = threadIdx.x; f < nfrag; f += 256) {
    int g = f >> 6, s = f & 63;
    int ks = g >> 1, mt = g & 1;
    int hi = s & 1, lr = s >> 1;
    const float* src = W + (ks * 16 + hi * 8) * 64 + (mt * 32 + lr);
    uint4 u;
    u.x = cvt_pk_bf16(src[0],   src[64]);
    u.y = cvt_pk_bf16(src[128], src[192]);
    u.z = cvt_pk_bf16(src[256], src[320]);
    u.w = cvt_pk_bf16(src[384], src[448]);
    *(uint4*)(wbuf + f * 16) = u;
  }
}

// ---------------------------------------------------------------------------
// One 32-row x 64-chan layer tile (verified r3..r23 math):
//   v_mfma_f32_32x32x16_bf16, D = W^T (A) x^T (B)
//     A: row=lane&31 (chan), k=(lane>>5)*8+j ; B: col=lane&31 (graph-row)
//     D: col=lane&31 (row), chan=(reg&3)+8*(reg>>2)+4*(lane>>5)
//   B-fragments preloaded (deep LDS pipeline), A-pairs JIT from the dense
//   per-layer LDS W buffer. LN(64) in-place + one shfl_xor(32).
//   Lanes lr>=vr produce garbage (contained: D-col==B-row) and are guarded.
// ---------------------------------------------------------------------------
template<int KS>
__device__ __forceinline__ void tile_layer(
    const char* __restrict__ wl,    // LDS W buffer (packed fragment order)
    char* __restrict__ xs, int xrow0, int vr,
    const float* __restrict__ Pb, const float* __restrict__ Pg,
    const float* __restrict__ Pn)
{
  const int lane = threadIdx.x & 63;
  const int lr   = lane & 31;
  const int hi   = lane >> 5;
  const int ch4  = hi * 4;
  const int br   = xrow0 + lr;
  const int wo   = (lr * 2 + hi) * 16;   // lane's byte offset within 1KB group

  // preload all B-fragments (independent LDS reads, deep pipeline)
  bf16x8 bfr[KS];
#pragma unroll
  for (int ks = 0; ks < KS; ++ks)
    bfr[ks] = *(const bf16x8*)(xs + xswz(br, ks * 32 + hi * 16));

  f32x16 acc0 = zero16(), acc1 = zero16();
#pragma unroll
  for (int ks = 0; ks < KS; ++ks) {
    bf16x8 a0 = *(const bf16x8*)(wl + (ks * 2 + 0) * 1024 + wo);
    bf16x8 a1 = *(const bf16x8*)(wl + (ks * 2 + 1) * 1024 + wo);
    acc0 = __builtin_amdgcn_mfma_f32_32x32x16_bf16(a0, bfr[ks], acc0, 0, 0, 0);
    acc1 = __builtin_amdgcn_mfma_f32_32x32x16_bf16(a1, bfr[ks], acc1, 0, 0, 0);
  }

  // ---- bias (in place) + LayerNorm(64) ----
#pragma unroll
  for (int b = 0; b < 4; ++b) {
    float4 t0 = *(const float4*)&Pb[8 * b + ch4];
    float4 t1 = *(const float4*)&Pb[32 + 8 * b + ch4];
    acc0[4*b+0] += t0.x; acc0[4*b+1] += t0.y;
    acc0[4*b+2] += t0.z; acc0[4*b+3] += t0.w;
    acc1[4*b+0] += t1.x; acc1[4*b+1] += t1.y;
    acc1[4*b+2] += t1.z; acc1[4*b+3] += t1.w;
  }
  float s = 0.f, q = 0.f;
#pragma unroll
  for (int r = 0; r < 16; ++r) {
    s += acc0[r] + acc1[r];
    q = fmaf(acc0[r], acc0[r], q);
    q = fmaf(acc1[r], acc1[r], q);
  }
  s += __shfl_xor(s, 32);
  q += __shfl_xor(q, 32);
  float mu   = s * 0.015625f;
  float rstd = rsqrtf(fmaf(q, 0.015625f, -mu * mu) + 1e-5f);

  // ---- gamma/beta + ReLU, pack bf16, guarded swizzled write ----
#pragma unroll
  for (int b = 0; b < 4; ++b) {
    float4 g0 = *(const float4*)&Pg[8 * b + ch4];
    float4 n0 = *(const float4*)&Pn[8 * b + ch4];
    float4 g1 = *(const float4*)&Pg[32 + 8 * b + ch4];
    float4 n1 = *(const float4*)&Pn[32 + 8 * b + ch4];
    float h00 = fmaxf(0.f, fmaf((acc0[4*b+0] - mu) * rstd, g0.x, n0.x));
    float h01 = fmaxf(0.f, fmaf((acc0[4*b+1] - mu) * rstd, g0.y, n0.y));
    float h02 = fmaxf(0.f, fmaf((acc0[4*b+2] - mu) * rstd, g0.z, n0.z));
    float h03 = fmaxf(0.f, fmaf((acc0[4*b+3] - mu) * rstd, g0.w, n0.w));
    float h10 = fmaxf(0.f, fmaf((acc1[4*b+0] - mu) * rstd, g1.x, n1.x));
    float h11 = fmaxf(0.f, fmaf((acc1[4*b+1] - mu) * rstd, g1.y, n1.y));
    float h12 = fmaxf(0.f, fmaf((acc1[4*b+2] - mu) * rstd, g1.z, n1.z));
    float h13 = fmaxf(0.f, fmaf((acc1[4*b+3] - mu) * rstd, g1.w, n1.w));
    if (lr < vr) {
      uint2 u0; u0.x = cvt_pk_bf16(h00, h01); u0.y = cvt_pk_bf16(h02, h03);
      uint2 u1; u1.x = cvt_pk_bf16(h10, h11); u1.y = cvt_pk_bf16(h12, h13);
      *(uint2*)(xs + xswz(br, 16 * b + 8 * hi)) = u0;
      *(uint2*)(xs + xswz(br, 64 + 16 * b + 8 * hi)) = u1;
    }
  }
}

// map neighbor-max (top-2) for graph g / channel c, register row cache;
// h>=0 so bf16 bits compare as uint16
__device__ __forceinline__ void nmax_one(char* xs, int g, int c) {
  const int rb = g * NM_;
  unsigned int xv[NM_];
  unsigned int m1 = 0, m2 = 0;
#pragma unroll
  for (int n = 0; n < NM_; ++n) {
    xv[n] = *(const ushort_t*)(xs + xswz(rb + n, 2 * c));
    if (xv[n] > m1) { m2 = m1; m1 = xv[n]; } else if (xv[n] > m2) m2 = xv[n];
  }
#pragma unroll
  for (int n = 0; n < NM_; ++n)
    *(ushort_t*)(xs + xswz(rb + n, 128 + 2 * c)) =
        (ushort_t)((xv[n] == m1) ? m2 : m1);
}

// agent-pair neighbor-max: threads 0..127 -> (g=tid>>6 row base g*64, c)
__device__ __forceinline__ void nmax_agent2(char* xs) {
  const int tid = threadIdx.x;
  if (tid >= 128) return;
  const int g = tid >> 6, c = tid & 63;
  const int rb = g * 64;
  unsigned int m1 = 0, m2 = 0;
  for (int n = 0; n < NA_; ++n) {
    unsigned int x = *(const ushort_t*)(xs + xswz(rb + n, 2 * c));
    if (x > m1) { m2 = m1; m1 = x; } else if (x > m2) m2 = x;
  }
  for (int n = 0; n < NA_; ++n) {
    unsigned int x = *(const ushort_t*)(xs + xswz(rb + n, 2 * c));
    *(ushort_t*)(xs + xswz(rb + n, 128 + 2 * c)) =
        (ushort_t)((x == m1) ? m2 : m1);
  }
}

__device__ __forceinline__ void stage_params(
    const float* b0, const float* g0, const float* n0,
    const float* b1, const float* g1, const float* n1,
    const float* b2, const float* g2, const float* n2, float* Pp)
{
  const int tid = threadIdx.x;
  if (tid < 64) {
    Pp[      tid] = b0[tid]; Pp[ 64 + tid] = g0[tid]; Pp[128 + tid] = n0[tid];
    Pp[192 + tid] = b1[tid]; Pp[256 + tid] = g1[tid]; Pp[320 + tid] = n1[tid];
    Pp[384 + tid] = b2[tid]; Pp[448 + tid] = g2[tid]; Pp[512 + tid] = n2[tid];
  }
}

// ---------------------------------------------------------------------------
__global__ __launch_bounds__(256, 3) void subnet16(
    const float* __restrict__ agent, const float* __restrict__ mapf,
    const float* __restrict__ aw0, const float* __restrict__ ab0,
    const float* __restrict__ ag0, const float* __restrict__ an0,
    const float* __restrict__ aw1, const float* __restrict__ ab1,
    const float* __restrict__ ag1, const float* __restrict__ an1,
    const float* __restrict__ aw2, const float* __restrict__ ab2,
    const float* __restrict__ ag2, const float* __restrict__ an2,
    const float* __restrict__ mw0, const float* __restrict__ mb0,
    const float* __restrict__ mg0, const float* __restrict__ mn0,
    const float* __restrict__ mw1, const float* __restrict__ mb1,
    const float* __restrict__ mg1, const float* __restrict__ mn1,
    const float* __restrict__ mw2, const float* __restrict__ mb2,
    const float* __restrict__ mg2, const float* __restrict__ mn2,
    const float* __restrict__ fcw, const float* __restrict__ attnw,
    float* __restrict__ feats, float* __restrict__ waswad)
{
  __shared__ __align__(16) char smem[SMEMB];
  char*  xs   = smem;
  char*  wbuf = smem + XBYTES;
  float* Pp   = (float*)(smem + XBYTES + WBBYTES);
  const int tid = threadIdx.x;
  const int wid = tid >> 6;

  if (blockIdx.x == AGRID + MGRID) {
    // ---- was/wad block: waswad = fcw @ attnw[:128], fcw @ attnw[128:] ----
    const int lane = tid & 63;
    float a0 = attnw[lane],       a1 = attnw[64 + lane];
    float dd0 = attnw[128 + lane], dd1 = attnw[192 + lane];
    for (int r = wid; r < 128; r += 4) {
      float w0 = fcw[r * 128 + lane], w1 = fcw[r * 128 + 64 + lane];
      float s1 = w0 * a0 + w1 * a1;
      float s2 = w0 * dd0 + w1 * dd1;
#pragma unroll
      for (int off = 32; off; off >>= 1) {
        s1 += __shfl_xor(s1, off);
        s2 += __shfl_xor(s2, off);
      }
      if (lane == 0) { waswad[r] = s1; waswad[128 + r] = s2; }
    }
    return;
  }

  if (blockIdx.x < AGRID) {
    // ---- agent: 2 graphs/block at row bases 0,64 (4 tiles, valid
    // 32,17,32,17), barriers; graphs 2*bid and 2*bid+1 ----
    const int bid = blockIdx.x;
    const int vr = (wid & 1) ? 17 : 32;
    for (int i = tid; i < 2 * NA_ * 16; i += 256) {
      int g = i / (NA_ * 16);
      int rem = i - g * (NA_ * 16);
      int row = rem >> 4, k4 = (rem & 15) * 4;
      float4 v = *(const float4*)&agent[((size_t)(2 * bid + g) * NA_ + row) * 64 + k4];
      uint2 u; u.x = cvt_pk_bf16(v.x, v.y); u.y = cvt_pk_bf16(v.z, v.w);
      *(uint2*)(xs + xswz(g * 64 + row, 8 * (rem & 15))) = u;
    }
    stage_w_direct<4>(aw0, wbuf);
    stage_params(ab0, ag0, an0, ab1, ag1, an1, ab2, ag2, an2, Pp);
    __syncthreads();
    tile_layer<4>(wbuf, xs, wid * 32, vr, Pp, Pp + 64, Pp + 128);
    __syncthreads();
    nmax_agent2(xs);
    stage_w_direct<8>(aw1, wbuf);
    __syncthreads();
    tile_layer<8>(wbuf, xs, wid * 32, vr, Pp + 192, Pp + 256, Pp + 320);
    __syncthreads();
    nmax_agent2(xs);
    stage_w_direct<8>(aw2, wbuf);
    __syncthreads();
    tile_layer<8>(wbuf, xs, wid * 32, vr, Pp + 384, Pp + 448, Pp + 512);
    __syncthreads();
    if (tid < 128) {  // poly per (g,c): both halves = max over 49 nodes
      const int g = tid >> 6, c = tid & 63;
      const int rb = g * 64;
      unsigned int m1 = 0;
      for (int n = 0; n < NA_; ++n) {
        unsigned int x = *(const ushort_t*)(xs + xswz(rb + n, 2 * c));
        m1 = x > m1 ? x : m1;
      }
      float f = __uint_as_float(m1 << 16);
      size_t slot = (size_t)(2 * bid + g);
      feats[slot * 128 + c] = f;
      feats[slot * 128 + 64 + c] = f;
    }
  } else {
    // ---- map: 6 graphs dense-packed (114 rows, 4 tiles -> 4 busy waves);
    // tail block ng=2 (38 rows). W direct-packed per layer into LDS;
    // restage overlaps nmax (disjoint LDS regions). Pad-row garbage is
    // confined to lanes lr>=vr (write-guarded; LN lane pairs share lr). ----
    const int mbid = blockIdx.x - AGRID;
    const int gbase = mbid * 6;
    const int ng = (gbase + 6 <= P_ * B_) ? 6 : (P_ * B_ - gbase);
    const int rows = ng * NM_;
    int vr = rows - wid * 32;       // this wave's valid rows in its tile
    vr = vr > 32 ? 32 : vr;
    for (int i = tid; i < rows * 16; i += 256) {
      int row = i >> 4, k4 = (i & 15) * 4;
      float4 v = *(const float4*)&mapf[((size_t)gbase * NM_ + row) * 64 + k4];
      uint2 u; u.x = cvt_pk_bf16(v.x, v.y); u.y = cvt_pk_bf16(v.z, v.w);
      *(uint2*)(xs + xswz(row, 8 * (i & 15))) = u;
    }
    stage_w_direct<4>(mw0, wbuf);
    stage_params(mb0, mg0, mn0, mb1, mg1, mn1, mb2, mg2, mn2, Pp);
    __syncthreads();
    if (vr > 0) tile_layer<4>(wbuf, xs, wid * 32, vr, Pp, Pp + 64, Pp + 128);
    __syncthreads();
    for (int i = tid; i < ng * 64; i += 256) nmax_one(xs, i >> 6, i & 63);
    stage_w_direct<8>(mw1, wbuf);
    __syncthreads();
    if (vr > 0) tile_layer<8>(wbuf, xs, wid * 32, vr,
                              Pp + 192, Pp + 256, Pp + 320);
    __syncthreads();
    for (int i = tid; i < ng * 64; i += 256) nmax_one(xs, i >> 6, i & 63);
    stage_w_direct<8>(mw2, wbuf);
    __syncthreads();
    if (vr > 0) tile_layer<8>(wbuf, xs, wid * 32, vr,
                              Pp + 384, Pp + 448, Pp + 512);
    __syncthreads();
    for (int i = tid; i < ng * 64; i += 256) {  // poly per (g,c)
      const int g = i >> 6, c = i & 63;
      const int rb = g * NM_;
      unsigned int m1 = 0;
      for (int n = 0; n < NM_; ++n) {
        unsigned int x = *(const ushort_t*)(xs + xswz(rb + n, 2 * c));
        m1 = x > m1 ? x : m1;
      }
      float f = __uint_as_float(m1 << 16);
      size_t slot = (size_t)(B_ + gbase + g);
      feats[slot * 128 + c] = f;
      feats[slot * 128 + 64 + c] = f;
    }
  }
}

// ---------------------------------------------------------------------------
// GAT (only destination node 0 is read) + readout MLP. One block per batch b.
// si phase: 2 threads per dot (halved serial length); rest full-block split.
// ---------------------------------------------------------------------------
__global__ __launch_bounds__(256) void gat_kernel(
    const float* __restrict__ feats,    // [129][B][128] fp32
    const float* __restrict__ fcw,      // [128][128]
    const float* __restrict__ waswad,   // [256] precomputed
    const float* __restrict__ mlpw,     // [128][60]
    const float* __restrict__ mlpb,     // [60]
    float* __restrict__ out)            // [B][60]
{
  const int b = blockIdx.x, tid = threadIdx.x;
  __shared__ float was[128], wad[128];
  __shared__ float si[130];
  __shared__ float alpha[128], red[8];
  __shared__ float up[2][128], ubuf[128], hgp[2][128], op[2][60];

  if (tid < 128) { was[tid] = waswad[tid]; wad[tid] = waswad[128 + tid]; }
  __syncthreads();

  {  // si[1..128]: 2 threads per dot (idx = tid>>1, halves of k)
    const int idx = tid >> 1, half = tid & 1;
    const float* fr = feats + ((size_t)(idx + 1) * B_ + b) * 128 + half * 64;
    const float* wa = was + half * 64;
    float s = 0.f;
    for (int k = 0; k < 64; k += 4) {
      float4 f = *(const float4*)&fr[k];
      s += f.x * wa[k] + f.y * wa[k + 1] + f.z * wa[k + 2] + f.w * wa[k + 3];
    }
    s += __shfl_xor(s, 1);
    if (half == 0) si[idx + 1] = s;
    if (tid < 2) {  // d0 = feats[node 0][b] . wad (threads 0,1 split k)
      const float* f0 = feats + (size_t)b * 128 + tid * 64;
      const float* wd = wad + tid * 64;
      float s2 = 0.f;
      for (int k = 0; k < 64; k += 4) {
        float4 f = *(const float4*)&f0[k];
        s2 += f.x * wd[k] + f.y * wd[k + 1] + f.z * wd[k + 2] + f.w * wd[k + 3];
      }
      s2 += __shfl_xor(s2, 1);
      if (tid == 0) si[129] = s2;
    }
  }
  __syncthreads();

  float d0 = si[129];
  float e = -3.4e38f;
  if (tid < 128) {
    float x = si[tid + 1] + d0;
    e = (x > 0.f) ? x : 0.01f * x;
  }
  float m = e;
#pragma unroll
  for (int off = 32; off; off >>= 1) m = fmaxf(m, __shfl_xor(m, off));
  if ((tid & 63) == 0) red[tid >> 6] = m;
  __syncthreads();
  float mx = fmaxf(red[0], red[1]);
  float p = (tid < 128) ? expf(e - mx) : 0.f;
  float s = p;
#pragma unroll
  for (int off = 32; off; off >>= 1) s += __shfl_xor(s, off);
  if ((tid & 63) == 0) red[4 + (tid >> 6)] = s;
  __syncthreads();
  float denom = red[4] + red[5];
  if (tid < 128) alpha[tid] = p / denom;
  __syncthreads();

  {  // u = sum_t alpha_t feats[t+1][b][:]  — split t over two halves
    const int c = tid & 127, h = tid >> 7;
    const float* fb = feats + ((size_t)(h * 64 + 1) * B_ + b) * 128 + c;
    float u = 0.f;
    for (int t = 0; t < 64; ++t)
      u += alpha[h * 64 + t] * fb[(size_t)t * B_ * 128];
    up[h][c] = u;
  }
  __syncthreads();
  if (tid < 128) ubuf[tid] = up[0][tid] + up[1][tid];
  __syncthreads();

  {  // hg = ubuf @ fcw — split k over two halves
    const int c = tid & 127, h = tid >> 7;
    float sacc = 0.f;
    for (int k = 0; k < 64; ++k)
      sacc += ubuf[h * 64 + k] * fcw[(h * 64 + k) * 128 + c];
    hgp[h][c] = sacc;
  }
  __syncthreads();

  if (tid < 120) {  // out = hg @ mlpw + mlpb — split c over two halves
    const int o = tid % 60, h = tid / 60;
    float sacc = 0.f;
    for (int c = 0; c < 64; ++c)
      sacc += (hgp[0][h * 64 + c] + hgp[1][h * 64 + c]) * mlpw[(h * 64 + c) * OUT_ + o];
    op[h][o] = sacc;
  }
  __syncthreads();
  if (tid < OUT_) out[b * OUT_ + tid] = mlpb[tid] + op[0][tid] + op[1][tid];
}

// ---------------------------------------------------------------------------
extern "C" void kernel_launch(void* const* d_in, const int* in_sizes, int n_in,
                              void* d_out, int out_size, void* d_ws, size_t ws_size,
                              hipStream_t stream) {
  (void)in_sizes; (void)n_in; (void)out_size; (void)ws_size;

  const float* agent = (const float*)d_in[0];   // [B][NA][64]
  const float* mapf  = (const float*)d_in[1];   // [P][B][NM][64]
  // d_in[2] = map_mask (all ones, unused)

  const float* aw0 = (const float*)d_in[3];
  const float* ab0 = (const float*)d_in[4];
  const float* ag0 = (const float*)d_in[5];
  const float* an0 = (const float*)d_in[6];
  const float* aw1 = (const float*)d_in[7];
  const float* ab1 = (const float*)d_in[8];
  const float* ag1 = (const float*)d_in[9];
  const float* an1 = (const float*)d_in[10];
  const float* aw2 = (const float*)d_in[11];
  const float* ab2 = (const float*)d_in[12];
  const float* ag2 = (const float*)d_in[13];
  const float* an2 = (const float*)d_in[14];

  const float* mw0 = (const float*)d_in[15];
  const float* mb0 = (const float*)d_in[16];
  const float* mg0 = (const float*)d_in[17];
  const float* mn0 = (const float*)d_in[18];
  const float* mw1 = (const float*)d_in[19];
  const float* mb1 = (const float*)d_in[20];
  const float* mg1 = (const float*)d_in[21];
  const float* mn1 = (const float*)d_in[22];
  const float* mw2 = (const float*)d_in[23];
  const float* mb2 = (const float*)d_in[24];
  const float* mg2 = (const float*)d_in[25];
  const float* mn2 = (const float*)d_in[26];

  const float* fcw   = (const float*)d_in[27];
  const float* attnw = (const float*)d_in[28];
  const float* mlpw  = (const float*)d_in[29];
  const float* mlpb  = (const float*)d_in[30];

  float* feats = (float*)d_ws;
  float* waswad = (float*)((char*)d_ws + FEATS_BYTES);
  float* out = (float*)d_out;

  // 1) fused agent(32) + map(1366) + waswad(1) subnet; W direct-packed
  //    per block into LDS via one uint4 write per fragment (conflict-free)
  subnet16<<<AGRID + MGRID + 1, 256, 0, stream>>>(
      agent, mapf,
      aw0, ab0, ag0, an0, aw1, ab1, ag1, an1, aw2, ab2, ag2, an2,
      mw0, mb0, mg0, mn0, mw1, mb1, mg1, mn1, mw2, mb2, mg2, mn2,
      fcw, attnw, feats, waswad);

  // 2) GAT column-0 + MLP readout (parallel si, full-block loops)
  gat_kernel<<<B_, 256, 0, stream>>>(feats, fcw, waswad, mlpw, mlpb, out);
}